// Round 11
// baseline (352.750 us; speedup 1.0000x reference)
//
#include <hip/hip_runtime.h>
#include <math.h>

#define B_ 256
#define E_ 128
#define N_ 128
#define T_ 20
#define D_ 128
#define M_ (B_*E_)   // 32768 sequences

typedef __attribute__((ext_vector_type(8))) short bf16x8;
typedef __attribute__((ext_vector_type(4))) short s16x4;
typedef __attribute__((ext_vector_type(4))) float f32x4;
typedef __attribute__((ext_vector_type(4))) unsigned u32x4;

__device__ __forceinline__ float sigm(float x) { return 1.0f / (1.0f + __expf(-x)); }
__device__ __forceinline__ float fast_tanh(float x) {
    float e = __expf(2.f * x);
    return 1.f - 2.f / (e + 1.f);
}
__device__ __forceinline__ short f2bf(float f) {   // RNE float->bf16 (scalar)
    unsigned u = __builtin_bit_cast(unsigned, f);
    u += 0x7fffu + ((u >> 16) & 1u);
    return (short)(u >> 16);
}
// HW packed convert: 2 f32 -> 2 bf16 in one instruction (RNE).
__device__ __forceinline__ unsigned cvtpk(float lo, float hi) {
    unsigned r;
    asm("v_cvt_pk_bf16_f32 %0, %1, %2" : "=v"(r) : "v"(lo), "v"(hi));
    return r;
}
__device__ __forceinline__ bf16x8 pk8(float4 a, float4 b) {
    u32x4 u = { cvtpk(a.x,a.y), cvtpk(a.z,a.w), cvtpk(b.x,b.y), cvtpk(b.z,b.w) };
    return __builtin_bit_cast(bf16x8, u);
}
__device__ __forceinline__ bf16x8 cvt8(const float* __restrict__ p) {
    float4 u = *(const float4*)p;
    float4 v = *(const float4*)(p + 4);
    return pk8(u, v);
}

// [rows][32k] bf16 slice, 64 B/row; chunk-XOR swizzle.
#define SLADDR(row, chunk) ((row) * 64 + ((((chunk) ^ ((row) >> 1)) & 3) << 4))

// [rows][128 cols bf16] tile, 256 B/row, byte-XOR swizzle.
__device__ __forceinline__ bf16x8 t_frag(const char* base, int row, int cb) {
    return *(const bf16x8*)(base + row * 256 + (cb ^ ((row & 7) << 4)));
}
// [rows][256 cols bf16] tile, 512 B/row, byte-XOR swizzle.
__device__ __forceinline__ bf16x8 t_frag512(const char* base, int row, int cb) {
    return *(const bf16x8*)(base + row * 512 + (cb ^ ((row & 7) << 4)));
}

// LDS-only barrier: drain LDS ops, sync, but DON'T drain vmcnt.
__device__ __forceinline__ void lds_barrier() {
    asm volatile("s_waitcnt lgkmcnt(0)" ::: "memory");
    __builtin_amdgcn_s_barrier();
    asm volatile("" ::: "memory");
}

// ---------------------------------------------------------------------------
// K0: deterministic counting sort of sequence indices by len (bins 1..20).
// Also emits rank[idx] = position (for k0x's scatter). No atomics.
// ---------------------------------------------------------------------------
__global__ __launch_bounds__(1024) void k0_sort(
    const int* __restrict__ len, int* __restrict__ perm, int* __restrict__ rank)
{
    __shared__ int wavehist[16][21];
    __shared__ int wavecur [16][21];
    const int tid  = threadIdx.x;
    const int lane = tid & 63;
    const int w    = tid >> 6;

    int cnt = 0;
#pragma unroll 1
    for (int it = 0; it < 32; ++it) {
        int v = len[w * 2048 + it * 64 + lane];
#pragma unroll
        for (int b = 1; b <= 20; ++b) {
            unsigned long long mask = __ballot(v == b);
            if (lane == b - 1) cnt += __popcll(mask);
        }
    }
    if (lane < 20) wavehist[w][lane + 1] = cnt;
    __syncthreads();

    if (tid == 0) {
        int run = 0;
        for (int b = 1; b <= 20; ++b)
            for (int wv = 0; wv < 16; ++wv) {
                int c = wavehist[wv][b];
                wavecur[wv][b] = run;
                run += c;
            }
    }
    __syncthreads();

#pragma unroll 1
    for (int it = 0; it < 32; ++it) {
        int idx = w * 2048 + it * 64 + lane;
        int v = len[idx];
#pragma unroll 1
        for (int b = 1; b <= 20; ++b) {
            unsigned long long mask = __ballot(v == b);
            if (mask) {
                int base = 0;
                if (lane == 0) {
                    base = wavecur[w][b];
                    wavecur[w][b] = base + __popcll(mask);
                }
                base = __shfl(base, 0, 64);
                if (v == b) {
                    int rk = __popcll(mask & ((1ull << lane) - 1ull));
                    perm[base + rk] = idx;
                    rank[idx] = base + rk;
                }
            }
        }
    }
}

// ---------------------------------------------------------------------------
// K0x: gather-copy X into chunk-contiguous bf16 tiles, length-trimmed.
// Xr layout: tile (c, t) at (c*20+t)*8192 bf16 elems = [64 rows][128 cols].
// Reads are per-seq CONTIGUOUS prefixes (len*512B streams); writes are 256B
// full-line bursts. 4096 blocks x 256 thr -> latency fully hidden by TLP.
// Rows for t >= len(seq) stay unwritten (stable poison; k1 predication
// discards those lanes' results; values are tiny finite bf16 -> no NaN).
// ---------------------------------------------------------------------------
__global__ __launch_bounds__(256) void k0x_pack(
    const float* __restrict__ xa, const int* __restrict__ len,
    const int* __restrict__ rank, short* __restrict__ Xr)
{
    const int tid   = threadIdx.x;
    const int m     = blockIdx.x * 8 + (tid >> 5);   // seq id
    const int lane  = tid & 31;
    const int pos   = rank[m];
    const int c     = pos >> 6;
    const int slot  = pos & 63;
    const int ln    = len[m];

    const float* src = xa + (size_t)m * (T_ * D_) + lane * 4;
    short* dstbase   = Xr + (size_t)(c * 20) * 8192 + slot * 128 + lane * 4;

#pragma unroll 1
    for (int t = 0; t < ln; ++t) {
        float4 v = *(const float4*)(src + (size_t)t * D_);
        uint2 o = { cvtpk(v.x, v.y), cvtpk(v.z, v.w) };
        *(uint2*)(dstbase + (size_t)t * 8192) = o;
    }
}

// ---------------------------------------------------------------------------
// K1: persistent MFMA micro-GRU over length-sorted chunks (R8 core).
// X now comes from the pre-packed bf16 Xr tiles: sequential 16 KB/step
// reads (L2-friendly), no f32->bf16 conversion in the hot loop, prefetch
// state shrinks 16 -> 4 VGPR. 512 thr / 8 waves / 64 seqs / mt=4.
// ---------------------------------------------------------------------------
__global__ __launch_bounds__(512, 2) void k1_gru_mfma(
    const short* __restrict__ Xr, const int* __restrict__ len,
    const int* __restrict__ perm,
    const float* __restrict__ wih, const float* __restrict__ whh,
    const float* __restrict__ bih, const float* __restrict__ bhh,
    short* __restrict__ mh)        // bf16 [M][128]
{
    __shared__ __align__(16) char Xb0[64 * 256];
    __shared__ __align__(16) char Xb1[64 * 256];
    __shared__ __align__(16) char Hb0[64 * 256];
    __shared__ __align__(16) char Hb1[64 * 256];
    __shared__ int pidx[64];
    __shared__ int lens_s[64];
    __shared__ int lmax_s;

    const int tid = threadIdx.x;
    const int l   = tid & 63;
    const int w   = tid >> 6;
    const int l15 = l & 15;
    const int l4  = l >> 4;

    bf16x8 wf[2][3][4];
#pragma unroll
    for (int s = 0; s < 2; ++s) {
        const float* W = s ? whh : wih;
#pragma unroll
        for (int g = 0; g < 3; ++g) {
            int grow = g * 128 + w * 16 + l15;
#pragma unroll
            for (int kt = 0; kt < 4; ++kt)
                wf[s][g][kt] = cvt8(W + (size_t)grow * 128 + kt * 32 + l4 * 8);
        }
    }

    const int dcol = w * 16 + l15;
    const float brz = bih[dcol]       + bhh[dcol];
    const float bzz = bih[128 + dcol] + bhh[128 + dcol];
    const float bin_= bih[256 + dcol];
    const float bhn_= bhh[256 + dcol];

    const int sr0 = tid >> 4;          // 0..31
    const int sc8 = (tid & 15) * 8;    // col in elems
    const int lbA = sr0 * 256 + ((sc8 * 2) ^ ((sr0 & 7) << 4));
    const int lbB = (sr0 + 32) * 256 + ((sc8 * 2) ^ (((sr0 + 32) & 7) << 4));

#pragma unroll 1
    for (int pass = 0; pass < 2; ++pass) {
        const int chunk = pass ? (511 - (int)blockIdx.x) : (int)blockIdx.x;

        __syncthreads();
        if (tid < 64) {
            int p = perm[chunk * 64 + tid];
            pidx[tid]   = p;
            lens_s[tid] = len[p];
        }
        __syncthreads();
        if (tid < 64) {
            int v = lens_s[tid];
#pragma unroll
            for (int o = 32; o; o >>= 1) v = max(v, __shfl_xor(v, o, 64));
            if (tid == 0) lmax_s = v;
        }

        int lenv[16];
#pragma unroll
        for (int mt = 0; mt < 4; ++mt)
#pragma unroll
            for (int r = 0; r < 4; ++r)
                lenv[mt * 4 + r] = lens_s[mt * 16 + l4 * 4 + r];

        // chunk-contiguous bf16 tiles: row sr0 / sr0+32, 16B per thread
        const short* xbA = Xr + (size_t)(chunk * 20) * 8192 + sr0 * 128 + sc8;
        const short* xbB = xbA + 32 * 128;

        // prologue: stage X_0; prefetch X_1 (tile may be unwritten if lmax==1 — harmless)
        *(bf16x8*)(Xb0 + lbA) = *(const bf16x8*)(xbA);
        *(bf16x8*)(Xb0 + lbB) = *(const bf16x8*)(xbB);
        bf16x8 xpA = *(const bf16x8*)(xbA + 8192);
        bf16x8 xpB = *(const bf16x8*)(xbB + 8192);

        __syncthreads();   // X_0 + lmax_s visible
        const int Lmax = lmax_s;

        float hm[4][4];
#pragma unroll
        for (int mt = 0; mt < 4; ++mt)
#pragma unroll
            for (int r = 0; r < 4; ++r) hm[mt][r] = 0.f;

        char* Xc = Xb0; char* Xn = Xb1;
        char* Hc = Hb0; char* Hn = Hb1;

#pragma unroll 1
        for (int t = 0; t < Lmax; ++t) {
            // 1) stage X_{t+1} from prefetch regs
            if (t + 1 < Lmax) {
                *(bf16x8*)(Xn + lbA) = xpA;
                *(bf16x8*)(Xn + lbB) = xpB;
            }
            // 2) issue X_{t+2} prefetch (stays in flight across the barrier)
            if (t + 2 < Lmax) {
                xpA = *(const bf16x8*)(xbA + (size_t)(t + 2) * 8192);
                xpB = *(const bf16x8*)(xbB + (size_t)(t + 2) * 8192);
            }

            // accumulators bias-initialized (C-in carries bias)
            f32x4 aR[4], aZ[4], aI[4], aH[4];
#pragma unroll
            for (int mt = 0; mt < 4; ++mt) {
                aR[mt] = (f32x4){brz, brz, brz, brz};
                aZ[mt] = (f32x4){bzz, bzz, bzz, bzz};
                aI[mt] = (f32x4){bin_, bin_, bin_, bin_};
                aH[mt] = (f32x4){bhn_, bhn_, bhn_, bhn_};
            }

            // 3) MFMA — X phase
#pragma unroll
            for (int kt = 0; kt < 4; ++kt) {
                const int cb = kt * 64 + l4 * 16;
#pragma unroll
                for (int mt = 0; mt < 4; ++mt) {
                    bf16x8 a = t_frag(Xc, mt * 16 + l15, cb);
                    aR[mt] = __builtin_amdgcn_mfma_f32_16x16x32_bf16(a, wf[0][0][kt], aR[mt], 0, 0, 0);
                    aZ[mt] = __builtin_amdgcn_mfma_f32_16x16x32_bf16(a, wf[0][1][kt], aZ[mt], 0, 0, 0);
                    aI[mt] = __builtin_amdgcn_mfma_f32_16x16x32_bf16(a, wf[0][2][kt], aI[mt], 0, 0, 0);
                }
            }
            //    MFMA — H phase (skip t=0: h=0 -> gh = bias only, already in C)
            if (t > 0) {
#pragma unroll
                for (int kt = 0; kt < 4; ++kt) {
                    const int cb = kt * 64 + l4 * 16;
#pragma unroll
                    for (int mt = 0; mt < 4; ++mt) {
                        bf16x8 a = t_frag(Hc, mt * 16 + l15, cb);
                        aR[mt] = __builtin_amdgcn_mfma_f32_16x16x32_bf16(a, wf[1][0][kt], aR[mt], 0, 0, 0);
                        aZ[mt] = __builtin_amdgcn_mfma_f32_16x16x32_bf16(a, wf[1][1][kt], aZ[mt], 0, 0, 0);
                        aH[mt] = __builtin_amdgcn_mfma_f32_16x16x32_bf16(a, wf[1][2][kt], aH[mt], 0, 0, 0);
                    }
                }
            }

            // 4) epilogue (lane-local); h_new = n + z*(h-n)
#pragma unroll
            for (int mt = 0; mt < 4; ++mt)
#pragma unroll
                for (int r = 0; r < 4; ++r) {
                    float rr = sigm(aR[mt][r]);
                    float zz = sigm(aZ[mt][r]);
                    float nn = fast_tanh(aI[mt][r] + rr * aH[mt][r]);
                    float hold = hm[mt][r];
                    float hnew = nn + zz * (hold - nn);
                    hm[mt][r] = (t < lenv[mt * 4 + r]) ? hnew : hold;
                }

            // 5) write h_{t+1} -> Hn; 6) LDS-only barrier
            if (t + 1 < Lmax) {
#pragma unroll
                for (int mt = 0; mt < 4; ++mt) {
#pragma unroll
                    for (int rp = 0; rp < 4; rp += 2) {
                        unsigned pk = cvtpk(hm[mt][rp], hm[mt][rp + 1]);
                        int row0 = mt * 16 + l4 * 4 + rp;
                        int row1 = row0 + 1;
                        *(short*)(Hn + row0 * 256 + ((dcol * 2) ^ ((row0 & 7) << 4))) = (short)(pk & 0xffff);
                        *(short*)(Hn + row1 * 256 + ((dcol * 2) ^ ((row1 & 7) << 4))) = (short)(pk >> 16);
                    }
                }
                lds_barrier();
                { char* tmp = Xc; Xc = Xn; Xn = tmp; }
                { char* tmp = Hc; Hc = Hn; Hn = tmp; }
            }
        }

        // final h -> mh (bf16, scattered by perm)
#pragma unroll
        for (int mt = 0; mt < 4; ++mt) {
#pragma unroll
            for (int r = 0; r < 4; ++r) {
                int m = pidx[mt * 16 + l4 * 4 + r];
                mh[(size_t)m * 128 + dcol] = f2bf(hm[mt][r]);
            }
        }
    }
}

// ---------------------------------------------------------------------------
// K23 (fused k2 + k3a + k3b): unchanged from round 10 (proven).
// ---------------------------------------------------------------------------
__global__ __launch_bounds__(512) void k23_fused(
    const float* __restrict__ A, const float* __restrict__ hidden,
    const float* __restrict__ mi, const short* __restrict__ mh,
    const float* __restrict__ w_in, const float* __restrict__ b_in,
    const float* __restrict__ w_out, const float* __restrict__ b_out,
    const float* __restrict__ b_iah, const float* __restrict__ b_ioh,
    const float* __restrict__ wih, const float* __restrict__ whh,
    const float* __restrict__ bih, const float* __restrict__ bhh,
    float* __restrict__ out)
{
    __shared__ __align__(16) char HIO[64 * 1024];
    __shared__ __align__(16) char INP[64 * 1024];
    __shared__ __align__(16) char STG[24 * 1024];

    const int tid = threadIdx.x;
    const int l = tid & 63, w = tid >> 6;
    const int l15 = l & 15, l4 = l >> 4;
    const int wr = w >> 1, wc = w & 1;
    const int b  = blockIdx.x;
    const int m0 = b * 128;

    char* As  = STG;
    char* Bs  = STG + 8 * 1024;
    const int srow = tid >> 2, sc4 = tid & 3;
    const int brow = tid >> 1, bh  = tid & 1;

    // ================= Phase 1: k2 -> hioT_lds =================
    {
        float bj[8];
#pragma unroll
        for (int cf = 0; cf < 8; ++cf) {
            int j = wc * 128 + cf * 16 + l15;
            bj[cf] = (j < 128) ? b_in[j] : b_out[j - 128];
        }
        f32x4 acc[2][8];
#pragma unroll
        for (int rf = 0; rf < 2; ++rf)
#pragma unroll
            for (int cf = 0; cf < 8; ++cf) acc[rf][cf] = (f32x4){0.f,0.f,0.f,0.f};

#pragma unroll 1
        for (int kt = 0; kt < 8; ++kt) {
            if (kt < 4) {
                *(bf16x8*)(As + SLADDR(srow, sc4)) =
                    cvt8(mi + (size_t)(m0 + srow) * 128 + kt * 32 + sc4 * 8);
            } else {
                *(bf16x8*)(As + SLADDR(srow, sc4)) =
                    *(const bf16x8*)(mh + (size_t)(m0 + srow) * 128 + (kt - 4) * 32 + sc4 * 8);
            }
            {
                const float* wsrc = (brow < 128)
                    ? (w_in  + (size_t)brow * 256 + kt * 32 + bh * 16)
                    : (w_out + (size_t)(brow - 128) * 256 + kt * 32 + bh * 16);
                *(bf16x8*)(Bs + SLADDR(brow, bh * 2    )) = cvt8(wsrc);
                *(bf16x8*)(Bs + SLADDR(brow, bh * 2 + 1)) = cvt8(wsrc + 8);
            }
            __syncthreads();
            bf16x8 af[2], bfr[8];
#pragma unroll
            for (int rf = 0; rf < 2; ++rf)
                af[rf] = *(const bf16x8*)(As + SLADDR(wr * 32 + rf * 16 + l15, l4));
#pragma unroll
            for (int cf = 0; cf < 8; ++cf)
                bfr[cf] = *(const bf16x8*)(Bs + SLADDR(wc * 128 + cf * 16 + l15, l4));
#pragma unroll
            for (int rf = 0; rf < 2; ++rf)
#pragma unroll
                for (int cf = 0; cf < 8; ++cf)
                    acc[rf][cf] = __builtin_amdgcn_mfma_f32_16x16x32_bf16(af[rf], bfr[cf], acc[rf][cf], 0, 0, 0);
            __syncthreads();
        }

#pragma unroll
        for (int rf = 0; rf < 2; ++rf)
#pragma unroll
            for (int cf = 0; cf < 8; ++cf) {
                int j  = wc * 128 + cf * 16 + l15;
                int e0 = wr * 32 + rf * 16 + l4 * 4;
                s16x4 s;
#pragma unroll
                for (int r = 0; r < 4; ++r) s[r] = f2bf(acc[rf][cf][r] + bj[cf]);
                *(s16x4*)(HIO + j * 256 + ((e0 * 2) ^ ((j & 7) << 4))) = s;
            }
        __syncthreads();
    }

    // ================= Phase 2: k3a -> inputs_lds =================
    {
        char* As0 = STG;
        char* As1 = STG + 8 * 1024;
        float bj[8];
#pragma unroll
        for (int cf = 0; cf < 8; ++cf) {
            int j = wc * 128 + cf * 16 + l15;
            bj[cf] = (j < 128) ? b_iah[j] : b_ioh[j - 128];
        }
        f32x4 acc[2][8];
#pragma unroll
        for (int rf = 0; rf < 2; ++rf)
#pragma unroll
            for (int cf = 0; cf < 8; ++cf) acc[rf][cf] = (f32x4){0.f,0.f,0.f,0.f};

        const float* Ab = A + (size_t)b * 128 * 256;
#pragma unroll 1
        for (int kt = 0; kt < 4; ++kt) {
            *(bf16x8*)(As0 + SLADDR(srow, sc4)) = cvt8(Ab + (size_t)srow * 256 +       kt * 32 + sc4 * 8);
            *(bf16x8*)(As1 + SLADDR(srow, sc4)) = cvt8(Ab + (size_t)srow * 256 + 128 + kt * 32 + sc4 * 8);
            __syncthreads();
            const char* Asel = wc ? As1 : As0;
            bf16x8 af[2], bfr[8];
#pragma unroll
            for (int rf = 0; rf < 2; ++rf)
                af[rf] = *(const bf16x8*)(Asel + SLADDR(wr * 32 + rf * 16 + l15, l4));
#pragma unroll
            for (int cf = 0; cf < 8; ++cf)
                bfr[cf] = t_frag(HIO, wc * 128 + cf * 16 + l15, kt * 64 + l4 * 16);
#pragma unroll
            for (int rf = 0; rf < 2; ++rf)
#pragma unroll
                for (int cf = 0; cf < 8; ++cf)
                    acc[rf][cf] = __builtin_amdgcn_mfma_f32_16x16x32_bf16(af[rf], bfr[cf], acc[rf][cf], 0, 0, 0);
            __syncthreads();
        }

#pragma unroll
        for (int rf = 0; rf < 2; ++rf)
#pragma unroll
            for (int cf = 0; cf < 8; ++cf) {
                int j = wc * 128 + cf * 16 + l15;
#pragma unroll
                for (int r = 0; r < 4; ++r) {
                    int n = wr * 32 + rf * 16 + l4 * 4 + r;
                    *(short*)(INP + n * 512 + ((j * 2) ^ ((n & 7) << 4))) = f2bf(acc[rf][cf][r] + bj[cf]);
                }
            }
        __syncthreads();
    }

    // ================= Phase 3: k3b -> out =================
    {
        char* Bs3 = STG;
        char* HID = HIO;

        float br[4], bz[4], bi[4], bh_[4];
#pragma unroll
        for (int p = 0; p < 4; ++p) {
            int d = (wc * 4 + p) * 16 + l15;
            br[p] = bih[d]       + bhh[d];
            bz[p] = bih[128 + d] + bhh[128 + d];
            bi[p] = bih[256 + d];
            bh_[p]= bhh[256 + d];
        }
        f32x4 aR[2][4], aZ[2][4], aI[2][4], aH[2][4];
#pragma unroll
        for (int rf = 0; rf < 2; ++rf)
#pragma unroll
            for (int p = 0; p < 4; ++p) {
                aR[rf][p] = (f32x4){0.f,0.f,0.f,0.f};
                aZ[rf][p] = (f32x4){0.f,0.f,0.f,0.f};
                aI[rf][p] = (f32x4){0.f,0.f,0.f,0.f};
                aH[rf][p] = (f32x4){0.f,0.f,0.f,0.f};
            }

#pragma unroll 1
        for (int kt = 0; kt < 12; ++kt) {
            if (kt >= 8) {
                const float* src = hidden + (size_t)(m0 + srow) * 128 + (kt - 8) * 32 + sc4 * 8;
                *(bf16x8*)(HID + SLADDR(srow, sc4)) = cvt8(src);
            }
#pragma unroll
            for (int i = 0; i < 3; ++i) {
                int c = tid + 512 * i;
                int row = c >> 2, ch = c & 3;
                const float* wsrc = (kt < 8)
                    ? (wih + (size_t)row * 256 + kt * 32 + ch * 8)
                    : (whh + (size_t)row * 128 + (kt - 8) * 32 + ch * 8);
                *(bf16x8*)(Bs3 + SLADDR(row, ch)) = cvt8(wsrc);
            }
            __syncthreads();

            bf16x8 a0, a1;
            if (kt < 8) {
                const int cb = kt * 64 + l4 * 16;
                a0 = t_frag512(INP, wr * 32 +      l15, cb);
                a1 = t_frag512(INP, wr * 32 + 16 + l15, cb);
            } else {
                a0 = *(const bf16x8*)(HID + SLADDR(wr * 32 +      l15, l4));
                a1 = *(const bf16x8*)(HID + SLADDR(wr * 32 + 16 + l15, l4));
            }
#pragma unroll
            for (int p = 0; p < 4; ++p) {
                int jb = (wc * 4 + p) * 16 + l15;
                bf16x8 bR = *(const bf16x8*)(Bs3 + SLADDR(      jb, l4));
                bf16x8 bZ = *(const bf16x8*)(Bs3 + SLADDR(128 + jb, l4));
                bf16x8 bN = *(const bf16x8*)(Bs3 + SLADDR(256 + jb, l4));
                aR[0][p] = __builtin_amdgcn_mfma_f32_16x16x32_bf16(a0, bR, aR[0][p], 0, 0, 0);
                aR[1][p] = __builtin_amdgcn_mfma_f32_16x16x32_bf16(a1, bR, aR[1][p], 0, 0, 0);
                aZ[0][p] = __builtin_amdgcn_mfma_f32_16x16x32_bf16(a0, bZ, aZ[0][p], 0, 0, 0);
                aZ[1][p] = __builtin_amdgcn_mfma_f32_16x16x32_bf16(a1, bZ, aZ[1][p], 0, 0, 0);
                if (kt < 8) {
                    aI[0][p] = __builtin_amdgcn_mfma_f32_16x16x32_bf16(a0, bN, aI[0][p], 0, 0, 0);
                    aI[1][p] = __builtin_amdgcn_mfma_f32_16x16x32_bf16(a1, bN, aI[1][p], 0, 0, 0);
                } else {
                    aH[0][p] = __builtin_amdgcn_mfma_f32_16x16x32_bf16(a0, bN, aH[0][p], 0, 0, 0);
                    aH[1][p] = __builtin_amdgcn_mfma_f32_16x16x32_bf16(a1, bN, aH[1][p], 0, 0, 0);
                }
            }
            __syncthreads();
        }

#pragma unroll
        for (int rf = 0; rf < 2; ++rf)
#pragma unroll
            for (int p = 0; p < 4; ++p) {
                int d = (wc * 4 + p) * 16 + l15;
#pragma unroll
                for (int r = 0; r < 4; ++r) {
                    int m = m0 + wr * 32 + rf * 16 + l4 * 4 + r;
                    float hv = hidden[(size_t)m * 128 + d];
                    float rg = sigm(aR[rf][p][r] + br[p]);
                    float zg = sigm(aZ[rf][p][r] + bz[p]);
                    float ng = fast_tanh(aI[rf][p][r] + bi[p] + rg * (aH[rf][p][r] + bh_[p]));
                    out[(size_t)m * 128 + d] = (1.f - zg) * hv + zg * ng;
                }
            }
    }
}

// ---------------------------------------------------------------------------
extern "C" void kernel_launch(void* const* d_in, const int* in_sizes, int n_in,
                              void* d_out, int out_size, void* d_ws, size_t ws_size,
                              hipStream_t stream) {
    const float* A     = (const float*)d_in[0];
    const float* hidden= (const float*)d_in[1];
    const float* mi    = (const float*)d_in[2];
    const float* xa    = (const float*)d_in[3];
    const int*   len   = (const int*)  d_in[4];
    const float* gwih  = (const float*)d_in[5];
    const float* gwhh  = (const float*)d_in[6];
    const float* gbih  = (const float*)d_in[7];
    const float* gbhh  = (const float*)d_in[8];
    const float* wih   = (const float*)d_in[9];
    const float* whh   = (const float*)d_in[10];
    const float* bih   = (const float*)d_in[11];
    const float* bhh   = (const float*)d_in[12];
    const float* biah  = (const float*)d_in[13];
    const float* bioh  = (const float*)d_in[14];
    const float* w_in  = (const float*)d_in[15];
    const float* b_in  = (const float*)d_in[16];
    const float* w_out = (const float*)d_in[17];
    const float* b_out = (const float*)d_in[18];

    float* out = (float*)d_out;
    // ws layout (~177 MB):
    //   [0, 8.39 MB):        mh bf16 [M][128]            (k1 -> k23)
    //   [8.39 MB, +128KB):   perm int [M]                (k0 -> k1)
    //   [+128KB, +128KB):    rank int [M]                (k0 -> k0x)
    //   [8.64 MB, +167.8MB): Xr bf16 [512*20][64][128]   (k0x -> k1)
    short* mh   = (short*)d_ws;
    int*   perm = (int*)((char*)d_ws + (size_t)M_ * D_ * 2);
    int*   rank = perm + M_;
    short* Xr   = (short*)((char*)d_ws + (size_t)M_ * D_ * 2 + 2 * (size_t)M_ * 4);

    k0_sort    <<<1,       1024, 0, stream>>>(len, perm, rank);
    k0x_pack   <<<M_ / 8,   256, 0, stream>>>(xa, len, rank, Xr);
    k1_gru_mfma<<<256,      512, 0, stream>>>(Xr, len, perm, gwih, gwhh, gbih, gbhh, mh);
    k23_fused  <<<B_,       512, 0, stream>>>(A, hidden, mi, mh,
                                              w_in, b_in, w_out, b_out,
                                              biah, bioh, wih, whh, bih, bhh, out);
}

// Round 12
// 304.142 us; speedup vs baseline: 1.1598x; 1.1598x over previous
//
#include <hip/hip_runtime.h>
#include <math.h>

#define B_ 256
#define E_ 128
#define N_ 128
#define T_ 20
#define D_ 128
#define M_ (B_*E_)   // 32768 sequences

typedef __attribute__((ext_vector_type(8))) short bf16x8;
typedef __attribute__((ext_vector_type(4))) short s16x4;
typedef __attribute__((ext_vector_type(4))) float f32x4;
typedef __attribute__((ext_vector_type(4))) unsigned u32x4;

__device__ __forceinline__ float sigm(float x) { return 1.0f / (1.0f + __expf(-x)); }
__device__ __forceinline__ float fast_tanh(float x) {
    float e = __expf(2.f * x);
    return 1.f - 2.f / (e + 1.f);
}
__device__ __forceinline__ short f2bf(float f) {   // RNE float->bf16 (scalar)
    unsigned u = __builtin_bit_cast(unsigned, f);
    u += 0x7fffu + ((u >> 16) & 1u);
    return (short)(u >> 16);
}
// HW packed convert: 2 f32 -> 2 bf16 in one instruction (RNE).
__device__ __forceinline__ unsigned cvtpk(float lo, float hi) {
    unsigned r;
    asm("v_cvt_pk_bf16_f32 %0, %1, %2" : "=v"(r) : "v"(lo), "v"(hi));
    return r;
}
__device__ __forceinline__ bf16x8 pk8(float4 a, float4 b) {
    u32x4 u = { cvtpk(a.x,a.y), cvtpk(a.z,a.w), cvtpk(b.x,b.y), cvtpk(b.z,b.w) };
    return __builtin_bit_cast(bf16x8, u);
}
__device__ __forceinline__ bf16x8 cvt8(const float* __restrict__ p) {
    float4 u = *(const float4*)p;
    float4 v = *(const float4*)(p + 4);
    return pk8(u, v);
}

// [rows][32k] bf16 slice, 64 B/row; chunk-XOR swizzle.
#define SLADDR(row, chunk) ((row) * 64 + ((((chunk) ^ ((row) >> 1)) & 3) << 4))

// [rows][128 cols bf16] tile, 256 B/row, byte-XOR swizzle.
__device__ __forceinline__ bf16x8 t_frag(const char* base, int row, int cb) {
    return *(const bf16x8*)(base + row * 256 + (cb ^ ((row & 7) << 4)));
}
// [rows][256 cols bf16] tile, 512 B/row, byte-XOR swizzle.
__device__ __forceinline__ bf16x8 t_frag512(const char* base, int row, int cb) {
    return *(const bf16x8*)(base + row * 512 + (cb ^ ((row & 7) << 4)));
}

// LDS-only barrier: drain LDS ops, sync, but DON'T drain vmcnt.
__device__ __forceinline__ void lds_barrier() {
    asm volatile("s_waitcnt lgkmcnt(0)" ::: "memory");
    __builtin_amdgcn_s_barrier();
    asm volatile("" ::: "memory");
}

// ---------------------------------------------------------------------------
// K0: deterministic counting sort of sequence indices by len (bins 1..20).
// Bin-major fill => within each 64-chunk, lens are NON-DECREASING, so the
// chunk max is the last element. No atomics. (Proven in R8/R10.)
// ---------------------------------------------------------------------------
__global__ __launch_bounds__(1024) void k0_sort(
    const int* __restrict__ len, int* __restrict__ perm)
{
    __shared__ int wavehist[16][21];
    __shared__ int wavecur [16][21];
    const int tid  = threadIdx.x;
    const int lane = tid & 63;
    const int w    = tid >> 6;

    int cnt = 0;
#pragma unroll 1
    for (int it = 0; it < 32; ++it) {
        int v = len[w * 2048 + it * 64 + lane];
#pragma unroll
        for (int b = 1; b <= 20; ++b) {
            unsigned long long mask = __ballot(v == b);
            if (lane == b - 1) cnt += __popcll(mask);
        }
    }
    if (lane < 20) wavehist[w][lane + 1] = cnt;
    __syncthreads();

    if (tid == 0) {
        int run = 0;
        for (int b = 1; b <= 20; ++b)
            for (int wv = 0; wv < 16; ++wv) {
                int c = wavehist[wv][b];
                wavecur[wv][b] = run;
                run += c;
            }
    }
    __syncthreads();

#pragma unroll 1
    for (int it = 0; it < 32; ++it) {
        int idx = w * 2048 + it * 64 + lane;
        int v = len[idx];
#pragma unroll 1
        for (int b = 1; b <= 20; ++b) {
            unsigned long long mask = __ballot(v == b);
            if (mask) {
                int base = 0;
                if (lane == 0) {
                    base = wavecur[w][b];
                    wavecur[w][b] = base + __popcll(mask);
                }
                base = __shfl(base, 0, 64);
                if (v == b) {
                    int rank = __popcll(mask & ((1ull << lane) - 1ull));
                    perm[base + rank] = idx;
                }
            }
        }
    }
}

// ---------------------------------------------------------------------------
// K1: persistent MFMA micro-GRU over length-sorted chunks (R10 core, VALU-
// trimmed). 512 thr / 8 waves / 64 seqs / mt=4 (~128 VGPR + 64 AGPR, no
// spill). Block b runs chunk b then chunk 511-b; loop to chunk lmax.
// VALU cuts vs R10: (1) bias enters through the FIRST MFMA's C operand
// (persistent f32x4 bias vectors) -> no per-step accumulator-init movs;
// (2) lmax = lens_s[63] (sorted chunk) -> no serial reduce.
// ---------------------------------------------------------------------------
__global__ __launch_bounds__(512, 2) void k1_gru_mfma(
    const float* __restrict__ xa, const int* __restrict__ len,
    const int* __restrict__ perm,
    const float* __restrict__ wih, const float* __restrict__ whh,
    const float* __restrict__ bih, const float* __restrict__ bhh,
    short* __restrict__ mh)        // bf16 [M][128]
{
    __shared__ __align__(16) char Xb0[64 * 256];
    __shared__ __align__(16) char Xb1[64 * 256];
    __shared__ __align__(16) char Hb0[64 * 256];
    __shared__ __align__(16) char Hb1[64 * 256];
    __shared__ int pidx[64];
    __shared__ int lens_s[64];

    const int tid = threadIdx.x;
    const int l   = tid & 63;
    const int w   = tid >> 6;     // wave id 0..7 = d-tile
    const int l15 = l & 15;
    const int l4  = l >> 4;

    bf16x8 wf[2][3][4];
#pragma unroll
    for (int s = 0; s < 2; ++s) {
        const float* W = s ? whh : wih;
#pragma unroll
        for (int g = 0; g < 3; ++g) {
            int grow = g * 128 + w * 16 + l15;
#pragma unroll
            for (int kt = 0; kt < 4; ++kt)
                wf[s][g][kt] = cvt8(W + (size_t)grow * 128 + kt * 32 + l4 * 8);
        }
    }

    const int dcol = w * 16 + l15;
    // persistent bias C-vectors (seed accumulators via MFMA C operand)
    const float brz = bih[dcol]       + bhh[dcol];
    const float bzz = bih[128 + dcol] + bhh[128 + dcol];
    const float bin_= bih[256 + dcol];
    const float bhn_= bhh[256 + dcol];
    const f32x4 bR4 = {brz, brz, brz, brz};
    const f32x4 bZ4 = {bzz, bzz, bzz, bzz};
    const f32x4 bI4 = {bin_, bin_, bin_, bin_};
    const f32x4 bH4 = {bhn_, bhn_, bhn_, bhn_};

    const int sr0 = tid >> 4;          // 0..31
    const int sc8 = (tid & 15) * 8;    // col in elems
    const int lbA = sr0 * 256 + ((sc8 * 2) ^ ((sr0 & 7) << 4));
    const int lbB = (sr0 + 32) * 256 + ((sc8 * 2) ^ (((sr0 + 32) & 7) << 4));

#pragma unroll 1
    for (int pass = 0; pass < 2; ++pass) {
        const int chunk = pass ? (511 - (int)blockIdx.x) : (int)blockIdx.x;

        __syncthreads();   // previous pass fully done with pidx/tiles
        if (tid < 64) {
            int p = perm[chunk * 64 + tid];
            pidx[tid]   = p;
            lens_s[tid] = len[p];
        }
        __syncthreads();

        int lenv[16];
#pragma unroll
        for (int mt = 0; mt < 4; ++mt)
#pragma unroll
            for (int r = 0; r < 4; ++r)
                lenv[mt * 4 + r] = lens_s[mt * 16 + l4 * 4 + r];

        const int Lmax = lens_s[63];   // sorted chunk: last element is max

        const int rA = pidx[sr0];
        const int rB = pidx[sr0 + 32];
        const float* xbA = xa + (size_t)rA * (T_ * D_) + sc8;
        const float* xbB = xa + (size_t)rB * (T_ * D_) + sc8;

        // prologue: stage X_0; issue prefetch of X_1 (always in-bounds)
        {
            const float4* pA = (const float4*)xbA;
            const float4* pB = (const float4*)xbB;
            *(bf16x8*)(Xb0 + lbA) = pk8(pA[0], pA[1]);
            *(bf16x8*)(Xb0 + lbB) = pk8(pB[0], pB[1]);
        }
        float4 xa0, xa1, xb0v, xb1v;
        {
            const float4* qA = (const float4*)(xbA + D_);
            const float4* qB = (const float4*)(xbB + D_);
            xa0 = qA[0]; xa1 = qA[1]; xb0v = qB[0]; xb1v = qB[1];
        }
        __syncthreads();   // X_0 visible

        float hm[4][4];
#pragma unroll
        for (int mt = 0; mt < 4; ++mt)
#pragma unroll
            for (int r = 0; r < 4; ++r) hm[mt][r] = 0.f;

        char* Xc = Xb0; char* Xn = Xb1;
        char* Hc = Hb0; char* Hn = Hb1;

#pragma unroll 1
        for (int t = 0; t < Lmax; ++t) {
            // 1) stage X_{t+1} from prefetch regs (vmcnt wait lands here)
            if (t + 1 < Lmax) {
                *(bf16x8*)(Xn + lbA) = pk8(xa0, xa1);
                *(bf16x8*)(Xn + lbB) = pk8(xb0v, xb1v);
            }
            // 2) issue X_{t+2} prefetch (stays in flight across the barrier)
            if (t + 2 < Lmax) {
                const float4* qA = (const float4*)(xbA + (t + 2) * D_);
                const float4* qB = (const float4*)(xbB + (t + 2) * D_);
                xa0 = qA[0]; xa1 = qA[1]; xb0v = qB[0]; xb1v = qB[1];
            }

            f32x4 aR[4], aZ[4], aI[4], aH[4];

            // 3) MFMA — X phase; kt=0 seeds the bias through the C operand
            {
                const int cb0 = l4 * 16;
#pragma unroll
                for (int mt = 0; mt < 4; ++mt) {
                    bf16x8 a = t_frag(Xc, mt * 16 + l15, cb0);
                    aR[mt] = __builtin_amdgcn_mfma_f32_16x16x32_bf16(a, wf[0][0][0], bR4, 0, 0, 0);
                    aZ[mt] = __builtin_amdgcn_mfma_f32_16x16x32_bf16(a, wf[0][1][0], bZ4, 0, 0, 0);
                    aI[mt] = __builtin_amdgcn_mfma_f32_16x16x32_bf16(a, wf[0][2][0], bI4, 0, 0, 0);
                }
            }
#pragma unroll
            for (int kt = 1; kt < 4; ++kt) {
                const int cb = kt * 64 + l4 * 16;
#pragma unroll
                for (int mt = 0; mt < 4; ++mt) {
                    bf16x8 a = t_frag(Xc, mt * 16 + l15, cb);
                    aR[mt] = __builtin_amdgcn_mfma_f32_16x16x32_bf16(a, wf[0][0][kt], aR[mt], 0, 0, 0);
                    aZ[mt] = __builtin_amdgcn_mfma_f32_16x16x32_bf16(a, wf[0][1][kt], aZ[mt], 0, 0, 0);
                    aI[mt] = __builtin_amdgcn_mfma_f32_16x16x32_bf16(a, wf[0][2][kt], aI[mt], 0, 0, 0);
                }
            }
            //    MFMA — H phase; kt=0 seeds bhn through C for aH.
            if (t > 0) {
                {
                    const int cb0 = l4 * 16;
#pragma unroll
                    for (int mt = 0; mt < 4; ++mt) {
                        bf16x8 a = t_frag(Hc, mt * 16 + l15, cb0);
                        aR[mt] = __builtin_amdgcn_mfma_f32_16x16x32_bf16(a, wf[1][0][0], aR[mt], 0, 0, 0);
                        aZ[mt] = __builtin_amdgcn_mfma_f32_16x16x32_bf16(a, wf[1][1][0], aZ[mt], 0, 0, 0);
                        aH[mt] = __builtin_amdgcn_mfma_f32_16x16x32_bf16(a, wf[1][2][0], bH4, 0, 0, 0);
                    }
                }
#pragma unroll
                for (int kt = 1; kt < 4; ++kt) {
                    const int cb = kt * 64 + l4 * 16;
#pragma unroll
                    for (int mt = 0; mt < 4; ++mt) {
                        bf16x8 a = t_frag(Hc, mt * 16 + l15, cb);
                        aR[mt] = __builtin_amdgcn_mfma_f32_16x16x32_bf16(a, wf[1][0][kt], aR[mt], 0, 0, 0);
                        aZ[mt] = __builtin_amdgcn_mfma_f32_16x16x32_bf16(a, wf[1][1][kt], aZ[mt], 0, 0, 0);
                        aH[mt] = __builtin_amdgcn_mfma_f32_16x16x32_bf16(a, wf[1][2][kt], aH[mt], 0, 0, 0);
                    }
                }
            } else {
#pragma unroll
                for (int mt = 0; mt < 4; ++mt) aH[mt] = bH4;   // h=0 -> gh_n = bias
            }

            // 4) epilogue (lane-local); h_new = n + z*(h-n)
#pragma unroll
            for (int mt = 0; mt < 4; ++mt)
#pragma unroll
                for (int r = 0; r < 4; ++r) {
                    float rr = sigm(aR[mt][r]);
                    float zz = sigm(aZ[mt][r]);
                    float nn = fast_tanh(aI[mt][r] + rr * aH[mt][r]);
                    float hold = hm[mt][r];
                    float hnew = nn + zz * (hold - nn);
                    hm[mt][r] = (t < lenv[mt * 4 + r]) ? hnew : hold;
                }

            // 5) write h_{t+1} -> Hn; 6) LDS-only barrier
            if (t + 1 < Lmax) {
#pragma unroll
                for (int mt = 0; mt < 4; ++mt) {
#pragma unroll
                    for (int rp = 0; rp < 4; rp += 2) {
                        unsigned pk = cvtpk(hm[mt][rp], hm[mt][rp + 1]);
                        int row0 = mt * 16 + l4 * 4 + rp;
                        int row1 = row0 + 1;
                        *(short*)(Hn + row0 * 256 + ((dcol * 2) ^ ((row0 & 7) << 4))) = (short)(pk & 0xffff);
                        *(short*)(Hn + row1 * 256 + ((dcol * 2) ^ ((row1 & 7) << 4))) = (short)(pk >> 16);
                    }
                }
                lds_barrier();
                { char* tmp = Xc; Xc = Xn; Xn = tmp; }
                { char* tmp = Hc; Hc = Hn; Hn = tmp; }
            }
        }

        // final h -> mh (bf16, scattered by perm; pidx stable until pass-top sync)
#pragma unroll
        for (int mt = 0; mt < 4; ++mt) {
#pragma unroll
            for (int r = 0; r < 4; ++r) {
                int m = pidx[mt * 16 + l4 * 4 + r];
                mh[(size_t)m * 128 + dcol] = f2bf(hm[mt][r]);
            }
        }
    }
}

// ---------------------------------------------------------------------------
// K23 (fused k2 + k3a + k3b): unchanged from round 10 (proven).
// ---------------------------------------------------------------------------
__global__ __launch_bounds__(512) void k23_fused(
    const float* __restrict__ A, const float* __restrict__ hidden,
    const float* __restrict__ mi, const short* __restrict__ mh,
    const float* __restrict__ w_in, const float* __restrict__ b_in,
    const float* __restrict__ w_out, const float* __restrict__ b_out,
    const float* __restrict__ b_iah, const float* __restrict__ b_ioh,
    const float* __restrict__ wih, const float* __restrict__ whh,
    const float* __restrict__ bih, const float* __restrict__ bhh,
    float* __restrict__ out)
{
    __shared__ __align__(16) char HIO[64 * 1024];
    __shared__ __align__(16) char INP[64 * 1024];
    __shared__ __align__(16) char STG[24 * 1024];

    const int tid = threadIdx.x;
    const int l = tid & 63, w = tid >> 6;
    const int l15 = l & 15, l4 = l >> 4;
    const int wr = w >> 1, wc = w & 1;
    const int b  = blockIdx.x;
    const int m0 = b * 128;

    char* As  = STG;
    char* Bs  = STG + 8 * 1024;
    const int srow = tid >> 2, sc4 = tid & 3;
    const int brow = tid >> 1, bh  = tid & 1;

    // ================= Phase 1: k2 -> hioT_lds =================
    {
        float bj[8];
#pragma unroll
        for (int cf = 0; cf < 8; ++cf) {
            int j = wc * 128 + cf * 16 + l15;
            bj[cf] = (j < 128) ? b_in[j] : b_out[j - 128];
        }
        f32x4 acc[2][8];
#pragma unroll
        for (int rf = 0; rf < 2; ++rf)
#pragma unroll
            for (int cf = 0; cf < 8; ++cf) acc[rf][cf] = (f32x4){0.f,0.f,0.f,0.f};

#pragma unroll 1
        for (int kt = 0; kt < 8; ++kt) {
            if (kt < 4) {
                *(bf16x8*)(As + SLADDR(srow, sc4)) =
                    cvt8(mi + (size_t)(m0 + srow) * 128 + kt * 32 + sc4 * 8);
            } else {
                *(bf16x8*)(As + SLADDR(srow, sc4)) =
                    *(const bf16x8*)(mh + (size_t)(m0 + srow) * 128 + (kt - 4) * 32 + sc4 * 8);
            }
            {
                const float* wsrc = (brow < 128)
                    ? (w_in  + (size_t)brow * 256 + kt * 32 + bh * 16)
                    : (w_out + (size_t)(brow - 128) * 256 + kt * 32 + bh * 16);
                *(bf16x8*)(Bs + SLADDR(brow, bh * 2    )) = cvt8(wsrc);
                *(bf16x8*)(Bs + SLADDR(brow, bh * 2 + 1)) = cvt8(wsrc + 8);
            }
            __syncthreads();
            bf16x8 af[2], bfr[8];
#pragma unroll
            for (int rf = 0; rf < 2; ++rf)
                af[rf] = *(const bf16x8*)(As + SLADDR(wr * 32 + rf * 16 + l15, l4));
#pragma unroll
            for (int cf = 0; cf < 8; ++cf)
                bfr[cf] = *(const bf16x8*)(Bs + SLADDR(wc * 128 + cf * 16 + l15, l4));
#pragma unroll
            for (int rf = 0; rf < 2; ++rf)
#pragma unroll
                for (int cf = 0; cf < 8; ++cf)
                    acc[rf][cf] = __builtin_amdgcn_mfma_f32_16x16x32_bf16(af[rf], bfr[cf], acc[rf][cf], 0, 0, 0);
            __syncthreads();
        }

#pragma unroll
        for (int rf = 0; rf < 2; ++rf)
#pragma unroll
            for (int cf = 0; cf < 8; ++cf) {
                int j  = wc * 128 + cf * 16 + l15;
                int e0 = wr * 32 + rf * 16 + l4 * 4;
                s16x4 s;
#pragma unroll
                for (int r = 0; r < 4; ++r) s[r] = f2bf(acc[rf][cf][r] + bj[cf]);
                *(s16x4*)(HIO + j * 256 + ((e0 * 2) ^ ((j & 7) << 4))) = s;
            }
        __syncthreads();
    }

    // ================= Phase 2: k3a -> inputs_lds =================
    {
        char* As0 = STG;
        char* As1 = STG + 8 * 1024;
        float bj[8];
#pragma unroll
        for (int cf = 0; cf < 8; ++cf) {
            int j = wc * 128 + cf * 16 + l15;
            bj[cf] = (j < 128) ? b_iah[j] : b_ioh[j - 128];
        }
        f32x4 acc[2][8];
#pragma unroll
        for (int rf = 0; rf < 2; ++rf)
#pragma unroll
            for (int cf = 0; cf < 8; ++cf) acc[rf][cf] = (f32x4){0.f,0.f,0.f,0.f};

        const float* Ab = A + (size_t)b * 128 * 256;
#pragma unroll 1
        for (int kt = 0; kt < 4; ++kt) {
            *(bf16x8*)(As0 + SLADDR(srow, sc4)) = cvt8(Ab + (size_t)srow * 256 +       kt * 32 + sc4 * 8);
            *(bf16x8*)(As1 + SLADDR(srow, sc4)) = cvt8(Ab + (size_t)srow * 256 + 128 + kt * 32 + sc4 * 8);
            __syncthreads();
            const char* Asel = wc ? As1 : As0;
            bf16x8 af[2], bfr[8];
#pragma unroll
            for (int rf = 0; rf < 2; ++rf)
                af[rf] = *(const bf16x8*)(Asel + SLADDR(wr * 32 + rf * 16 + l15, l4));
#pragma unroll
            for (int cf = 0; cf < 8; ++cf)
                bfr[cf] = t_frag(HIO, wc * 128 + cf * 16 + l15, kt * 64 + l4 * 16);
#pragma unroll
            for (int rf = 0; rf < 2; ++rf)
#pragma unroll
                for (int cf = 0; cf < 8; ++cf)
                    acc[rf][cf] = __builtin_amdgcn_mfma_f32_16x16x32_bf16(af[rf], bfr[cf], acc[rf][cf], 0, 0, 0);
            __syncthreads();
        }

#pragma unroll
        for (int rf = 0; rf < 2; ++rf)
#pragma unroll
            for (int cf = 0; cf < 8; ++cf) {
                int j = wc * 128 + cf * 16 + l15;
#pragma unroll
                for (int r = 0; r < 4; ++r) {
                    int n = wr * 32 + rf * 16 + l4 * 4 + r;
                    *(short*)(INP + n * 512 + ((j * 2) ^ ((n & 7) << 4))) = f2bf(acc[rf][cf][r] + bj[cf]);
                }
            }
        __syncthreads();
    }

    // ================= Phase 3: k3b -> out =================
    {
        char* Bs3 = STG;
        char* HID = HIO;

        float br[4], bz[4], bi[4], bh_[4];
#pragma unroll
        for (int p = 0; p < 4; ++p) {
            int d = (wc * 4 + p) * 16 + l15;
            br[p] = bih[d]       + bhh[d];
            bz[p] = bih[128 + d] + bhh[128 + d];
            bi[p] = bih[256 + d];
            bh_[p]= bhh[256 + d];
        }
        f32x4 aR[2][4], aZ[2][4], aI[2][4], aH[2][4];
#pragma unroll
        for (int rf = 0; rf < 2; ++rf)
#pragma unroll
            for (int p = 0; p < 4; ++p) {
                aR[rf][p] = (f32x4){0.f,0.f,0.f,0.f};
                aZ[rf][p] = (f32x4){0.f,0.f,0.f,0.f};
                aI[rf][p] = (f32x4){0.f,0.f,0.f,0.f};
                aH[rf][p] = (f32x4){0.f,0.f,0.f,0.f};
            }

#pragma unroll 1
        for (int kt = 0; kt < 12; ++kt) {
            if (kt >= 8) {
                const float* src = hidden + (size_t)(m0 + srow) * 128 + (kt - 8) * 32 + sc4 * 8;
                *(bf16x8*)(HID + SLADDR(srow, sc4)) = cvt8(src);
            }
#pragma unroll
            for (int i = 0; i < 3; ++i) {
                int c = tid + 512 * i;
                int row = c >> 2, ch = c & 3;
                const float* wsrc = (kt < 8)
                    ? (wih + (size_t)row * 256 + kt * 32 + ch * 8)
                    : (whh + (size_t)row * 128 + (kt - 8) * 32 + ch * 8);
                *(bf16x8*)(Bs3 + SLADDR(row, ch)) = cvt8(wsrc);
            }
            __syncthreads();

            bf16x8 a0, a1;
            if (kt < 8) {
                const int cb = kt * 64 + l4 * 16;
                a0 = t_frag512(INP, wr * 32 +      l15, cb);
                a1 = t_frag512(INP, wr * 32 + 16 + l15, cb);
            } else {
                a0 = *(const bf16x8*)(HID + SLADDR(wr * 32 +      l15, l4));
                a1 = *(const bf16x8*)(HID + SLADDR(wr * 32 + 16 + l15, l4));
            }
#pragma unroll
            for (int p = 0; p < 4; ++p) {
                int jb = (wc * 4 + p) * 16 + l15;
                bf16x8 bR = *(const bf16x8*)(Bs3 + SLADDR(      jb, l4));
                bf16x8 bZ = *(const bf16x8*)(Bs3 + SLADDR(128 + jb, l4));
                bf16x8 bN = *(const bf16x8*)(Bs3 + SLADDR(256 + jb, l4));
                aR[0][p] = __builtin_amdgcn_mfma_f32_16x16x32_bf16(a0, bR, aR[0][p], 0, 0, 0);
                aR[1][p] = __builtin_amdgcn_mfma_f32_16x16x32_bf16(a1, bR, aR[1][p], 0, 0, 0);
                aZ[0][p] = __builtin_amdgcn_mfma_f32_16x16x32_bf16(a0, bZ, aZ[0][p], 0, 0, 0);
                aZ[1][p] = __builtin_amdgcn_mfma_f32_16x16x32_bf16(a1, bZ, aZ[1][p], 0, 0, 0);
                if (kt < 8) {
                    aI[0][p] = __builtin_amdgcn_mfma_f32_16x16x32_bf16(a0, bN, aI[0][p], 0, 0, 0);
                    aI[1][p] = __builtin_amdgcn_mfma_f32_16x16x32_bf16(a1, bN, aI[1][p], 0, 0, 0);
                } else {
                    aH[0][p] = __builtin_amdgcn_mfma_f32_16x16x32_bf16(a0, bN, aH[0][p], 0, 0, 0);
                    aH[1][p] = __builtin_amdgcn_mfma_f32_16x16x32_bf16(a1, bN, aH[1][p], 0, 0, 0);
                }
            }
            __syncthreads();
        }

#pragma unroll
        for (int rf = 0; rf < 2; ++rf)
#pragma unroll
            for (int p = 0; p < 4; ++p) {
                int d = (wc * 4 + p) * 16 + l15;
#pragma unroll
                for (int r = 0; r < 4; ++r) {
                    int m = m0 + wr * 32 + rf * 16 + l4 * 4 + r;
                    float hv = hidden[(size_t)m * 128 + d];
                    float rg = sigm(aR[rf][p][r] + br[p]);
                    float zg = sigm(aZ[rf][p][r] + bz[p]);
                    float ng = fast_tanh(aI[rf][p][r] + bi[p] + rg * (aH[rf][p][r] + bh_[p]));
                    out[(size_t)m * 128 + d] = (1.f - zg) * hv + zg * ng;
                }
            }
    }
}

// ---------------------------------------------------------------------------
extern "C" void kernel_launch(void* const* d_in, const int* in_sizes, int n_in,
                              void* d_out, int out_size, void* d_ws, size_t ws_size,
                              hipStream_t stream) {
    const float* A     = (const float*)d_in[0];
    const float* hidden= (const float*)d_in[1];
    const float* mi    = (const float*)d_in[2];
    const float* xa    = (const float*)d_in[3];
    const int*   len   = (const int*)  d_in[4];
    const float* gwih  = (const float*)d_in[5];
    const float* gwhh  = (const float*)d_in[6];
    const float* gbih  = (const float*)d_in[7];
    const float* gbhh  = (const float*)d_in[8];
    const float* wih   = (const float*)d_in[9];
    const float* whh   = (const float*)d_in[10];
    const float* bih   = (const float*)d_in[11];
    const float* bhh   = (const float*)d_in[12];
    const float* biah  = (const float*)d_in[13];
    const float* bioh  = (const float*)d_in[14];
    const float* w_in  = (const float*)d_in[15];
    const float* b_in  = (const float*)d_in[16];
    const float* w_out = (const float*)d_in[17];
    const float* b_out = (const float*)d_in[18];

    float* out = (float*)d_out;
    // ws layout (8.5 MB):
    //   [0, 8.39 MB):      mh bf16 [M][128]   (k1 -> k23)
    //   [8.39 MB, +128KB): perm int [M]       (k0 -> k1)
    short* mh   = (short*)d_ws;
    int*   perm = (int*)((char*)d_ws + (size_t)M_ * D_ * 2);

    k0_sort    <<<1,      1024, 0, stream>>>(len, perm);
    k1_gru_mfma<<<256,     512, 0, stream>>>(xa, len, perm, gwih, gwhh, gbih, gbhh, mh);
    k23_fused  <<<B_,      512, 0, stream>>>(A, hidden, mi, mh,
                                             w_in, b_in, w_out, b_out,
                                             biah, bioh, wih, whh, bih, bhh, out);
}

// Round 13
// 285.927 us; speedup vs baseline: 1.2337x; 1.0637x over previous
//
#include <hip/hip_runtime.h>
#include <math.h>

#define B_ 256
#define E_ 128
#define N_ 128
#define T_ 20
#define D_ 128
#define M_ (B_*E_)   // 32768 sequences

typedef __attribute__((ext_vector_type(8))) short bf16x8;
typedef __attribute__((ext_vector_type(4))) short s16x4;
typedef __attribute__((ext_vector_type(4))) float f32x4;
typedef __attribute__((ext_vector_type(4))) unsigned u32x4;

__device__ __forceinline__ float sigm(float x) { return 1.0f / (1.0f + __expf(-x)); }
__device__ __forceinline__ float fast_tanh(float x) {
    float e = __expf(2.f * x);
    return 1.f - 2.f / (e + 1.f);
}
__device__ __forceinline__ short f2bf(float f) {   // RNE float->bf16 (scalar)
    unsigned u = __builtin_bit_cast(unsigned, f);
    u += 0x7fffu + ((u >> 16) & 1u);
    return (short)(u >> 16);
}
// HW packed convert: 2 f32 -> 2 bf16 in one instruction (RNE).
__device__ __forceinline__ unsigned cvtpk(float lo, float hi) {
    unsigned r;
    asm("v_cvt_pk_bf16_f32 %0, %1, %2" : "=v"(r) : "v"(lo), "v"(hi));
    return r;
}
__device__ __forceinline__ bf16x8 pk8(float4 a, float4 b) {
    u32x4 u = { cvtpk(a.x,a.y), cvtpk(a.z,a.w), cvtpk(b.x,b.y), cvtpk(b.z,b.w) };
    return __builtin_bit_cast(bf16x8, u);
}
__device__ __forceinline__ bf16x8 cvt8(const float* __restrict__ p) {
    float4 u = *(const float4*)p;
    float4 v = *(const float4*)(p + 4);
    return pk8(u, v);
}

// [rows][32k] bf16 slice, 64 B/row; chunk-XOR swizzle.
#define SLADDR(row, chunk) ((row) * 64 + ((((chunk) ^ ((row) >> 1)) & 3) << 4))

// [rows][128 cols bf16] tile, 256 B/row, byte-XOR swizzle.
__device__ __forceinline__ bf16x8 t_frag(const char* base, int row, int cb) {
    return *(const bf16x8*)(base + row * 256 + (cb ^ ((row & 7) << 4)));
}
// [rows][256 cols bf16] tile, 512 B/row, byte-XOR swizzle.
__device__ __forceinline__ bf16x8 t_frag512(const char* base, int row, int cb) {
    return *(const bf16x8*)(base + row * 512 + (cb ^ ((row & 7) << 4)));
}

// LDS-only barrier: drain LDS ops, sync, but DON'T drain vmcnt.
__device__ __forceinline__ void lds_barrier() {
    asm volatile("s_waitcnt lgkmcnt(0)" ::: "memory");
    __builtin_amdgcn_s_barrier();
    asm volatile("" ::: "memory");
}

// ---------------------------------------------------------------------------
// K0: deterministic counting sort of sequence indices by len (bins 1..20).
// Bin-major fill => within each 64-chunk lens are NON-DECREASING (max = last).
// ---------------------------------------------------------------------------
__global__ __launch_bounds__(1024) void k0_sort(
    const int* __restrict__ len, int* __restrict__ perm)
{
    __shared__ int wavehist[16][21];
    __shared__ int wavecur [16][21];
    const int tid  = threadIdx.x;
    const int lane = tid & 63;
    const int w    = tid >> 6;

    int cnt = 0;
#pragma unroll 1
    for (int it = 0; it < 32; ++it) {
        int v = len[w * 2048 + it * 64 + lane];
#pragma unroll
        for (int b = 1; b <= 20; ++b) {
            unsigned long long mask = __ballot(v == b);
            if (lane == b - 1) cnt += __popcll(mask);
        }
    }
    if (lane < 20) wavehist[w][lane + 1] = cnt;
    __syncthreads();

    if (tid == 0) {
        int run = 0;
        for (int b = 1; b <= 20; ++b)
            for (int wv = 0; wv < 16; ++wv) {
                int c = wavehist[wv][b];
                wavecur[wv][b] = run;
                run += c;
            }
    }
    __syncthreads();

#pragma unroll 1
    for (int it = 0; it < 32; ++it) {
        int idx = w * 2048 + it * 64 + lane;
        int v = len[idx];
#pragma unroll 1
        for (int b = 1; b <= 20; ++b) {
            unsigned long long mask = __ballot(v == b);
            if (mask) {
                int base = 0;
                if (lane == 0) {
                    base = wavecur[w][b];
                    wavecur[w][b] = base + __popcll(mask);
                }
                base = __shfl(base, 0, 64);
                if (v == b) {
                    int rank = __popcll(mask & ((1ull << lane) - 1ull));
                    perm[base + rank] = idx;
                }
            }
        }
    }
}

// ---------------------------------------------------------------------------
// K1: persistent MFMA micro-GRU, SOFTWARE-PIPELINED X phase.
// 512 thr / 8 waves / 64 seqs / mt=4, ~192 unified regs (proven no-spill).
// X is TRIPLE-buffered: at step t the loop reads X(t+1) (for next-step
// re-seed) and writes X(t+2). Step structure:
//   a) stage X(t+2), issue prefetch X(t+3)
//   b) H-phase MFMA(t) (only MFMA block on the barrier critical path)
//   c) per-mt: epilogue(t) -> h-write(t+1) -> RE-SEED aR/aZ/aI with
//      X-phase(t+1) MFMAs (bias in C) -- MFMA issue overlaps epilogue VALU
//   d) LDS-only barrier
// ---------------------------------------------------------------------------
__global__ __launch_bounds__(512, 2) void k1_gru_mfma(
    const float* __restrict__ xa, const int* __restrict__ len,
    const int* __restrict__ perm,
    const float* __restrict__ wih, const float* __restrict__ whh,
    const float* __restrict__ bih, const float* __restrict__ bhh,
    short* __restrict__ mh)        // bf16 [M][128]
{
    __shared__ __align__(16) char XbB[3][64 * 256];
    __shared__ __align__(16) char Hb0[64 * 256];
    __shared__ __align__(16) char Hb1[64 * 256];
    __shared__ int pidx[64];
    __shared__ int lens_s[64];

    const int tid = threadIdx.x;
    const int l   = tid & 63;
    const int w   = tid >> 6;     // wave id 0..7 = d-tile
    const int l15 = l & 15;
    const int l4  = l >> 4;

    bf16x8 wf[2][3][4];
#pragma unroll
    for (int s = 0; s < 2; ++s) {
        const float* W = s ? whh : wih;
#pragma unroll
        for (int g = 0; g < 3; ++g) {
            int grow = g * 128 + w * 16 + l15;
#pragma unroll
            for (int kt = 0; kt < 4; ++kt)
                wf[s][g][kt] = cvt8(W + (size_t)grow * 128 + kt * 32 + l4 * 8);
        }
    }

    const int dcol = w * 16 + l15;
    const float brz = bih[dcol]       + bhh[dcol];
    const float bzz = bih[128 + dcol] + bhh[128 + dcol];
    const float bin_= bih[256 + dcol];
    const float bhn_= bhh[256 + dcol];
    const f32x4 bR4 = {brz, brz, brz, brz};
    const f32x4 bZ4 = {bzz, bzz, bzz, bzz};
    const f32x4 bI4 = {bin_, bin_, bin_, bin_};
    const f32x4 bH4 = {bhn_, bhn_, bhn_, bhn_};

    const int sr0 = tid >> 4;          // 0..31
    const int sc8 = (tid & 15) * 8;    // col in elems
    const int lbA = sr0 * 256 + ((sc8 * 2) ^ ((sr0 & 7) << 4));
    const int lbB = (sr0 + 32) * 256 + ((sc8 * 2) ^ (((sr0 + 32) & 7) << 4));

#pragma unroll 1
    for (int pass = 0; pass < 2; ++pass) {
        const int chunk = pass ? (511 - (int)blockIdx.x) : (int)blockIdx.x;

        __syncthreads();   // previous pass fully done with pidx/tiles
        if (tid < 64) {
            int p = perm[chunk * 64 + tid];
            pidx[tid]   = p;
            lens_s[tid] = len[p];
        }
        __syncthreads();

        int lenv[16];
#pragma unroll
        for (int mt = 0; mt < 4; ++mt)
#pragma unroll
            for (int r = 0; r < 4; ++r)
                lenv[mt * 4 + r] = lens_s[mt * 16 + l4 * 4 + r];

        const int Lmax = lens_s[63];   // sorted chunk: last element is max

        const int rA = pidx[sr0];
        const int rB = pidx[sr0 + 32];
        const float* xbA = xa + (size_t)rA * (T_ * D_) + sc8;
        const float* xbB = xa + (size_t)rB * (T_ * D_) + sc8;

        // prologue: stage X0 -> buf0, X1 -> buf1; prefetch X2 (T=20 bounds ok)
        {
            const float4* pA = (const float4*)xbA;
            const float4* pB = (const float4*)xbB;
            *(bf16x8*)(XbB[0] + lbA) = pk8(pA[0], pA[1]);
            *(bf16x8*)(XbB[0] + lbB) = pk8(pB[0], pB[1]);
            const float4* qA = (const float4*)(xbA + D_);
            const float4* qB = (const float4*)(xbB + D_);
            *(bf16x8*)(XbB[1] + lbA) = pk8(qA[0], qA[1]);
            *(bf16x8*)(XbB[1] + lbB) = pk8(qB[0], qB[1]);
        }
        float4 xa0, xa1, xb0v, xb1v;
        {
            const float4* qA = (const float4*)(xbA + 2 * D_);
            const float4* qB = (const float4*)(xbB + 2 * D_);
            xa0 = qA[0]; xa1 = qA[1]; xb0v = qB[0]; xb1v = qB[1];
        }
        lds_barrier();   // X0, X1 visible

        // seed acc with X-phase(0) (bias in C at kt=0); aH = bias (h=0)
        f32x4 aR[4], aZ[4], aI[4], aH[4];
        {
            const char* X0 = XbB[0];
            const int cb0 = l4 * 16;
#pragma unroll
            for (int mt = 0; mt < 4; ++mt) {
                bf16x8 a = t_frag(X0, mt * 16 + l15, cb0);
                aR[mt] = __builtin_amdgcn_mfma_f32_16x16x32_bf16(a, wf[0][0][0], bR4, 0, 0, 0);
                aZ[mt] = __builtin_amdgcn_mfma_f32_16x16x32_bf16(a, wf[0][1][0], bZ4, 0, 0, 0);
                aI[mt] = __builtin_amdgcn_mfma_f32_16x16x32_bf16(a, wf[0][2][0], bI4, 0, 0, 0);
            }
#pragma unroll
            for (int kt = 1; kt < 4; ++kt) {
                const int cb = kt * 64 + l4 * 16;
#pragma unroll
                for (int mt = 0; mt < 4; ++mt) {
                    bf16x8 a = t_frag(X0, mt * 16 + l15, cb);
                    aR[mt] = __builtin_amdgcn_mfma_f32_16x16x32_bf16(a, wf[0][0][kt], aR[mt], 0, 0, 0);
                    aZ[mt] = __builtin_amdgcn_mfma_f32_16x16x32_bf16(a, wf[0][1][kt], aZ[mt], 0, 0, 0);
                    aI[mt] = __builtin_amdgcn_mfma_f32_16x16x32_bf16(a, wf[0][2][kt], aI[mt], 0, 0, 0);
                }
            }
#pragma unroll
            for (int mt = 0; mt < 4; ++mt) aH[mt] = bH4;
        }

        float hm[4][4];
#pragma unroll
        for (int mt = 0; mt < 4; ++mt)
#pragma unroll
            for (int r = 0; r < 4; ++r) hm[mt][r] = 0.f;

        // X buffer roles at step t: R = X(t+1), W = X(t+2) slot, S = X(t) dead
        char* Xr_ = XbB[1];
        char* Xw_ = XbB[2];
        char* Xs_ = XbB[0];
        char* Hc = Hb0; char* Hn = Hb1;

#pragma unroll 1
        for (int t = 0; t < Lmax; ++t) {
            // a) stage X(t+2) from prefetch regs; issue prefetch X(t+3)
            if (t + 2 < Lmax) {
                *(bf16x8*)(Xw_ + lbA) = pk8(xa0, xa1);
                *(bf16x8*)(Xw_ + lbB) = pk8(xb0v, xb1v);
            }
            if (t + 3 < Lmax) {
                const float4* qA = (const float4*)(xbA + (t + 3) * D_);
                const float4* qB = (const float4*)(xbB + (t + 3) * D_);
                xa0 = qA[0]; xa1 = qA[1]; xb0v = qB[0]; xb1v = qB[1];
            }

            // b) H-phase MFMA(t): accumulate onto X-seeded acc; aH seeded at kt=0
            if (t > 0) {
                const int cb0 = l4 * 16;
#pragma unroll
                for (int mt = 0; mt < 4; ++mt) {
                    bf16x8 a = t_frag(Hc, mt * 16 + l15, cb0);
                    aR[mt] = __builtin_amdgcn_mfma_f32_16x16x32_bf16(a, wf[1][0][0], aR[mt], 0, 0, 0);
                    aZ[mt] = __builtin_amdgcn_mfma_f32_16x16x32_bf16(a, wf[1][1][0], aZ[mt], 0, 0, 0);
                    aH[mt] = __builtin_amdgcn_mfma_f32_16x16x32_bf16(a, wf[1][2][0], bH4, 0, 0, 0);
                }
#pragma unroll
                for (int kt = 1; kt < 4; ++kt) {
                    const int cb = kt * 64 + l4 * 16;
#pragma unroll
                    for (int mt = 0; mt < 4; ++mt) {
                        bf16x8 a = t_frag(Hc, mt * 16 + l15, cb);
                        aR[mt] = __builtin_amdgcn_mfma_f32_16x16x32_bf16(a, wf[1][0][kt], aR[mt], 0, 0, 0);
                        aZ[mt] = __builtin_amdgcn_mfma_f32_16x16x32_bf16(a, wf[1][1][kt], aZ[mt], 0, 0, 0);
                        aH[mt] = __builtin_amdgcn_mfma_f32_16x16x32_bf16(a, wf[1][2][kt], aH[mt], 0, 0, 0);
                    }
                }
            }

            // c) per-mt: epilogue(t) -> h-write(t+1) -> re-seed X-phase(t+1)
            const bool more = (t + 1 < Lmax);
#pragma unroll
            for (int mt = 0; mt < 4; ++mt) {
                // epilogue (lane-local); h_new = n + z*(h-n)
#pragma unroll
                for (int r = 0; r < 4; ++r) {
                    float rr = sigm(aR[mt][r]);
                    float zz = sigm(aZ[mt][r]);
                    float nn = fast_tanh(aI[mt][r] + rr * aH[mt][r]);
                    float hold = hm[mt][r];
                    float hnew = nn + zz * (hold - nn);
                    hm[mt][r] = (t < lenv[mt * 4 + r]) ? hnew : hold;
                }
                if (more) {
                    // h-write to Hn
#pragma unroll
                    for (int rp = 0; rp < 4; rp += 2) {
                        unsigned pk = cvtpk(hm[mt][rp], hm[mt][rp + 1]);
                        int row0 = mt * 16 + l4 * 4 + rp;
                        int row1 = row0 + 1;
                        *(short*)(Hn + row0 * 256 + ((dcol * 2) ^ ((row0 & 7) << 4))) = (short)(pk & 0xffff);
                        *(short*)(Hn + row1 * 256 + ((dcol * 2) ^ ((row1 & 7) << 4))) = (short)(pk >> 16);
                    }
                    // re-seed this mt with X-phase(t+1) — overlaps other mts' VALU
                    {
                        const int cb0 = l4 * 16;
                        bf16x8 a = t_frag(Xr_, mt * 16 + l15, cb0);
                        aR[mt] = __builtin_amdgcn_mfma_f32_16x16x32_bf16(a, wf[0][0][0], bR4, 0, 0, 0);
                        aZ[mt] = __builtin_amdgcn_mfma_f32_16x16x32_bf16(a, wf[0][1][0], bZ4, 0, 0, 0);
                        aI[mt] = __builtin_amdgcn_mfma_f32_16x16x32_bf16(a, wf[0][2][0], bI4, 0, 0, 0);
                    }
#pragma unroll
                    for (int kt = 1; kt < 4; ++kt) {
                        const int cb = kt * 64 + l4 * 16;
                        bf16x8 a = t_frag(Xr_, mt * 16 + l15, cb);
                        aR[mt] = __builtin_amdgcn_mfma_f32_16x16x32_bf16(a, wf[0][0][kt], aR[mt], 0, 0, 0);
                        aZ[mt] = __builtin_amdgcn_mfma_f32_16x16x32_bf16(a, wf[0][1][kt], aZ[mt], 0, 0, 0);
                        aI[mt] = __builtin_amdgcn_mfma_f32_16x16x32_bf16(a, wf[0][2][kt], aI[mt], 0, 0, 0);
                    }
                }
            }

            // d) barrier; rotate X buffers (R,W,S) <- (W,S,R); swap H buffers
            if (more) {
                lds_barrier();
                char* tmp = Xr_; Xr_ = Xw_; Xw_ = Xs_; Xs_ = tmp;
                char* th = Hc; Hc = Hn; Hn = th;
            }
        }

        // final h -> mh (bf16, scattered by perm)
#pragma unroll
        for (int mt = 0; mt < 4; ++mt) {
#pragma unroll
            for (int r = 0; r < 4; ++r) {
                int m = pidx[mt * 16 + l4 * 4 + r];
                mh[(size_t)m * 128 + dcol] = f2bf(hm[mt][r]);
            }
        }
    }
}

// ---------------------------------------------------------------------------
// K23 (fused k2 + k3a + k3b): unchanged from round 10/12 (proven).
// ---------------------------------------------------------------------------
__global__ __launch_bounds__(512) void k23_fused(
    const float* __restrict__ A, const float* __restrict__ hidden,
    const float* __restrict__ mi, const short* __restrict__ mh,
    const float* __restrict__ w_in, const float* __restrict__ b_in,
    const float* __restrict__ w_out, const float* __restrict__ b_out,
    const float* __restrict__ b_iah, const float* __restrict__ b_ioh,
    const float* __restrict__ wih, const float* __restrict__ whh,
    const float* __restrict__ bih, const float* __restrict__ bhh,
    float* __restrict__ out)
{
    __shared__ __align__(16) char HIO[64 * 1024];
    __shared__ __align__(16) char INP[64 * 1024];
    __shared__ __align__(16) char STG[24 * 1024];

    const int tid = threadIdx.x;
    const int l = tid & 63, w = tid >> 6;
    const int l15 = l & 15, l4 = l >> 4;
    const int wr = w >> 1, wc = w & 1;
    const int b  = blockIdx.x;
    const int m0 = b * 128;

    char* As  = STG;
    char* Bs  = STG + 8 * 1024;
    const int srow = tid >> 2, sc4 = tid & 3;
    const int brow = tid >> 1, bh  = tid & 1;

    // ================= Phase 1: k2 -> hioT_lds =================
    {
        float bj[8];
#pragma unroll
        for (int cf = 0; cf < 8; ++cf) {
            int j = wc * 128 + cf * 16 + l15;
            bj[cf] = (j < 128) ? b_in[j] : b_out[j - 128];
        }
        f32x4 acc[2][8];
#pragma unroll
        for (int rf = 0; rf < 2; ++rf)
#pragma unroll
            for (int cf = 0; cf < 8; ++cf) acc[rf][cf] = (f32x4){0.f,0.f,0.f,0.f};

#pragma unroll 1
        for (int kt = 0; kt < 8; ++kt) {
            if (kt < 4) {
                *(bf16x8*)(As + SLADDR(srow, sc4)) =
                    cvt8(mi + (size_t)(m0 + srow) * 128 + kt * 32 + sc4 * 8);
            } else {
                *(bf16x8*)(As + SLADDR(srow, sc4)) =
                    *(const bf16x8*)(mh + (size_t)(m0 + srow) * 128 + (kt - 4) * 32 + sc4 * 8);
            }
            {
                const float* wsrc = (brow < 128)
                    ? (w_in  + (size_t)brow * 256 + kt * 32 + bh * 16)
                    : (w_out + (size_t)(brow - 128) * 256 + kt * 32 + bh * 16);
                *(bf16x8*)(Bs + SLADDR(brow, bh * 2    )) = cvt8(wsrc);
                *(bf16x8*)(Bs + SLADDR(brow, bh * 2 + 1)) = cvt8(wsrc + 8);
            }
            __syncthreads();
            bf16x8 af[2], bfr[8];
#pragma unroll
            for (int rf = 0; rf < 2; ++rf)
                af[rf] = *(const bf16x8*)(As + SLADDR(wr * 32 + rf * 16 + l15, l4));
#pragma unroll
            for (int cf = 0; cf < 8; ++cf)
                bfr[cf] = *(const bf16x8*)(Bs + SLADDR(wc * 128 + cf * 16 + l15, l4));
#pragma unroll
            for (int rf = 0; rf < 2; ++rf)
#pragma unroll
                for (int cf = 0; cf < 8; ++cf)
                    acc[rf][cf] = __builtin_amdgcn_mfma_f32_16x16x32_bf16(af[rf], bfr[cf], acc[rf][cf], 0, 0, 0);
            __syncthreads();
        }

#pragma unroll
        for (int rf = 0; rf < 2; ++rf)
#pragma unroll
            for (int cf = 0; cf < 8; ++cf) {
                int j  = wc * 128 + cf * 16 + l15;
                int e0 = wr * 32 + rf * 16 + l4 * 4;
                s16x4 s;
#pragma unroll
                for (int r = 0; r < 4; ++r) s[r] = f2bf(acc[rf][cf][r] + bj[cf]);
                *(s16x4*)(HIO + j * 256 + ((e0 * 2) ^ ((j & 7) << 4))) = s;
            }
        __syncthreads();
    }

    // ================= Phase 2: k3a -> inputs_lds =================
    {
        char* As0 = STG;
        char* As1 = STG + 8 * 1024;
        float bj[8];
#pragma unroll
        for (int cf = 0; cf < 8; ++cf) {
            int j = wc * 128 + cf * 16 + l15;
            bj[cf] = (j < 128) ? b_iah[j] : b_ioh[j - 128];
        }
        f32x4 acc[2][8];
#pragma unroll
        for (int rf = 0; rf < 2; ++rf)
#pragma unroll
            for (int cf = 0; cf < 8; ++cf) acc[rf][cf] = (f32x4){0.f,0.f,0.f,0.f};

        const float* Ab = A + (size_t)b * 128 * 256;
#pragma unroll 1
        for (int kt = 0; kt < 4; ++kt) {
            *(bf16x8*)(As0 + SLADDR(srow, sc4)) = cvt8(Ab + (size_t)srow * 256 +       kt * 32 + sc4 * 8);
            *(bf16x8*)(As1 + SLADDR(srow, sc4)) = cvt8(Ab + (size_t)srow * 256 + 128 + kt * 32 + sc4 * 8);
            __syncthreads();
            const char* Asel = wc ? As1 : As0;
            bf16x8 af[2], bfr[8];
#pragma unroll
            for (int rf = 0; rf < 2; ++rf)
                af[rf] = *(const bf16x8*)(Asel + SLADDR(wr * 32 + rf * 16 + l15, l4));
#pragma unroll
            for (int cf = 0; cf < 8; ++cf)
                bfr[cf] = t_frag(HIO, wc * 128 + cf * 16 + l15, kt * 64 + l4 * 16);
#pragma unroll
            for (int rf = 0; rf < 2; ++rf)
#pragma unroll
                for (int cf = 0; cf < 8; ++cf)
                    acc[rf][cf] = __builtin_amdgcn_mfma_f32_16x16x32_bf16(af[rf], bfr[cf], acc[rf][cf], 0, 0, 0);
            __syncthreads();
        }

#pragma unroll
        for (int rf = 0; rf < 2; ++rf)
#pragma unroll
            for (int cf = 0; cf < 8; ++cf) {
                int j = wc * 128 + cf * 16 + l15;
#pragma unroll
                for (int r = 0; r < 4; ++r) {
                    int n = wr * 32 + rf * 16 + l4 * 4 + r;
                    *(short*)(INP + n * 512 + ((j * 2) ^ ((n & 7) << 4))) = f2bf(acc[rf][cf][r] + bj[cf]);
                }
            }
        __syncthreads();
    }

    // ================= Phase 3: k3b -> out =================
    {
        char* Bs3 = STG;
        char* HID = HIO;

        float br[4], bz[4], bi[4], bh_[4];
#pragma unroll
        for (int p = 0; p < 4; ++p) {
            int d = (wc * 4 + p) * 16 + l15;
            br[p] = bih[d]       + bhh[d];
            bz[p] = bih[128 + d] + bhh[128 + d];
            bi[p] = bih[256 + d];
            bh_[p]= bhh[256 + d];
        }
        f32x4 aR[2][4], aZ[2][4], aI[2][4], aH[2][4];
#pragma unroll
        for (int rf = 0; rf < 2; ++rf)
#pragma unroll
            for (int p = 0; p < 4; ++p) {
                aR[rf][p] = (f32x4){0.f,0.f,0.f,0.f};
                aZ[rf][p] = (f32x4){0.f,0.f,0.f,0.f};
                aI[rf][p] = (f32x4){0.f,0.f,0.f,0.f};
                aH[rf][p] = (f32x4){0.f,0.f,0.f,0.f};
            }

#pragma unroll 1
        for (int kt = 0; kt < 12; ++kt) {
            if (kt >= 8) {
                const float* src = hidden + (size_t)(m0 + srow) * 128 + (kt - 8) * 32 + sc4 * 8;
                *(bf16x8*)(HID + SLADDR(srow, sc4)) = cvt8(src);
            }
#pragma unroll
            for (int i = 0; i < 3; ++i) {
                int c = tid + 512 * i;
                int row = c >> 2, ch = c & 3;
                const float* wsrc = (kt < 8)
                    ? (wih + (size_t)row * 256 + kt * 32 + ch * 8)
                    : (whh + (size_t)row * 128 + (kt - 8) * 32 + ch * 8);
                *(bf16x8*)(Bs3 + SLADDR(row, ch)) = cvt8(wsrc);
            }
            __syncthreads();

            bf16x8 a0, a1;
            if (kt < 8) {
                const int cb = kt * 64 + l4 * 16;
                a0 = t_frag512(INP, wr * 32 +      l15, cb);
                a1 = t_frag512(INP, wr * 32 + 16 + l15, cb);
            } else {
                a0 = *(const bf16x8*)(HID + SLADDR(wr * 32 +      l15, l4));
                a1 = *(const bf16x8*)(HID + SLADDR(wr * 32 + 16 + l15, l4));
            }
#pragma unroll
            for (int p = 0; p < 4; ++p) {
                int jb = (wc * 4 + p) * 16 + l15;
                bf16x8 bR = *(const bf16x8*)(Bs3 + SLADDR(      jb, l4));
                bf16x8 bZ = *(const bf16x8*)(Bs3 + SLADDR(128 + jb, l4));
                bf16x8 bN = *(const bf16x8*)(Bs3 + SLADDR(256 + jb, l4));
                aR[0][p] = __builtin_amdgcn_mfma_f32_16x16x32_bf16(a0, bR, aR[0][p], 0, 0, 0);
                aR[1][p] = __builtin_amdgcn_mfma_f32_16x16x32_bf16(a1, bR, aR[1][p], 0, 0, 0);
                aZ[0][p] = __builtin_amdgcn_mfma_f32_16x16x32_bf16(a0, bZ, aZ[0][p], 0, 0, 0);
                aZ[1][p] = __builtin_amdgcn_mfma_f32_16x16x32_bf16(a1, bZ, aZ[1][p], 0, 0, 0);
                if (kt < 8) {
                    aI[0][p] = __builtin_amdgcn_mfma_f32_16x16x32_bf16(a0, bN, aI[0][p], 0, 0, 0);
                    aI[1][p] = __builtin_amdgcn_mfma_f32_16x16x32_bf16(a1, bN, aI[1][p], 0, 0, 0);
                } else {
                    aH[0][p] = __builtin_amdgcn_mfma_f32_16x16x32_bf16(a0, bN, aH[0][p], 0, 0, 0);
                    aH[1][p] = __builtin_amdgcn_mfma_f32_16x16x32_bf16(a1, bN, aH[1][p], 0, 0, 0);
                }
            }
            __syncthreads();
        }

#pragma unroll
        for (int rf = 0; rf < 2; ++rf)
#pragma unroll
            for (int p = 0; p < 4; ++p) {
                int d = (wc * 4 + p) * 16 + l15;
#pragma unroll
                for (int r = 0; r < 4; ++r) {
                    int m = m0 + wr * 32 + rf * 16 + l4 * 4 + r;
                    float hv = hidden[(size_t)m * 128 + d];
                    float rg = sigm(aR[rf][p][r] + br[p]);
                    float zg = sigm(aZ[rf][p][r] + bz[p]);
                    float ng = fast_tanh(aI[rf][p][r] + bi[p] + rg * (aH[rf][p][r] + bh_[p]));
                    out[(size_t)m * 128 + d] = (1.f - zg) * hv + zg * ng;
                }
            }
    }
}

// ---------------------------------------------------------------------------
extern "C" void kernel_launch(void* const* d_in, const int* in_sizes, int n_in,
                              void* d_out, int out_size, void* d_ws, size_t ws_size,
                              hipStream_t stream) {
    const float* A     = (const float*)d_in[0];
    const float* hidden= (const float*)d_in[1];
    const float* mi    = (const float*)d_in[2];
    const float* xa    = (const float*)d_in[3];
    const int*   len   = (const int*)  d_in[4];
    const float* gwih  = (const float*)d_in[5];
    const float* gwhh  = (const float*)d_in[6];
    const float* gbih  = (const float*)d_in[7];
    const float* gbhh  = (const float*)d_in[8];
    const float* wih   = (const float*)d_in[9];
    const float* whh   = (const float*)d_in[10];
    const float* bih   = (const float*)d_in[11];
    const float* bhh   = (const float*)d_in[12];
    const float* biah  = (const float*)d_in[13];
    const float* bioh  = (const float*)d_in[14];
    const float* w_in  = (const float*)d_in[15];
    const float* b_in  = (const float*)d_in[16];
    const float* w_out = (const float*)d_in[17];
    const float* b_out = (const float*)d_in[18];

    float* out = (float*)d_out;
    // ws layout (8.5 MB):
    //   [0, 8.39 MB):      mh bf16 [M][128]   (k1 -> k23)
    //   [8.39 MB, +128KB): perm int [M]       (k0 -> k1)
    short* mh   = (short*)d_ws;
    int*   perm = (int*)((char*)d_ws + (size_t)M_ * D_ * 2);

    k0_sort    <<<1,      1024, 0, stream>>>(len, perm);
    k1_gru_mfma<<<256,     512, 0, stream>>>(xa, len, perm, gwih, gwhh, gbih, gbhh, mh);
    k23_fused  <<<B_,      512, 0, stream>>>(A, hidden, mi, mh,
                                             w_in, b_in, w_out, b_out,
                                             biah, bioh, wih, whh, bih, bhh, out);
}

// Round 14
// 279.000 us; speedup vs baseline: 1.2643x; 1.0248x over previous
//
#include <hip/hip_runtime.h>
#include <math.h>

#define B_ 256
#define E_ 128
#define N_ 128
#define T_ 20
#define D_ 128
#define M_ (B_*E_)   // 32768 sequences

typedef __attribute__((ext_vector_type(8))) short bf16x8;
typedef __attribute__((ext_vector_type(4))) short s16x4;
typedef __attribute__((ext_vector_type(4))) float f32x4;
typedef __attribute__((ext_vector_type(4))) unsigned u32x4;

__device__ __forceinline__ float sigm(float x) { return 1.0f / (1.0f + __expf(-x)); }
__device__ __forceinline__ float fast_tanh(float x) {
    float e = __expf(2.f * x);
    return 1.f - 2.f / (e + 1.f);
}
__device__ __forceinline__ short f2bf(float f) {   // RNE float->bf16 (scalar)
    unsigned u = __builtin_bit_cast(unsigned, f);
    u += 0x7fffu + ((u >> 16) & 1u);
    return (short)(u >> 16);
}
// HW packed convert: 2 f32 -> 2 bf16 in one instruction (RNE).
__device__ __forceinline__ unsigned cvtpk(float lo, float hi) {
    unsigned r;
    asm("v_cvt_pk_bf16_f32 %0, %1, %2" : "=v"(r) : "v"(lo), "v"(hi));
    return r;
}
__device__ __forceinline__ bf16x8 pk8(float4 a, float4 b) {
    u32x4 u = { cvtpk(a.x,a.y), cvtpk(a.z,a.w), cvtpk(b.x,b.y), cvtpk(b.z,b.w) };
    return __builtin_bit_cast(bf16x8, u);
}
__device__ __forceinline__ bf16x8 cvt8(const float* __restrict__ p) {
    float4 u = *(const float4*)p;
    float4 v = *(const float4*)(p + 4);
    return pk8(u, v);
}

// [rows][32k] bf16 slice, 64 B/row; chunk-XOR swizzle.
#define SLADDR(row, chunk) ((row) * 64 + ((((chunk) ^ ((row) >> 1)) & 3) << 4))

// [rows][128 cols bf16] tile, 256 B/row, byte-XOR swizzle.
__device__ __forceinline__ bf16x8 t_frag(const char* base, int row, int cb) {
    return *(const bf16x8*)(base + row * 256 + (cb ^ ((row & 7) << 4)));
}
// [rows][256 cols bf16] tile, 512 B/row, byte-XOR swizzle.
__device__ __forceinline__ bf16x8 t_frag512(const char* base, int row, int cb) {
    return *(const bf16x8*)(base + row * 512 + (cb ^ ((row & 7) << 4)));
}

// LDS-only barrier: drain LDS ops, sync, but DON'T drain vmcnt.
__device__ __forceinline__ void lds_barrier() {
    asm volatile("s_waitcnt lgkmcnt(0)" ::: "memory");
    __builtin_amdgcn_s_barrier();
    asm volatile("" ::: "memory");
}

// ---------------------------------------------------------------------------
// K0: deterministic counting sort of sequence indices by len (bins 1..20).
// Bin-major fill => within each 64-chunk lens are NON-DECREASING (max = last).
// ---------------------------------------------------------------------------
__global__ __launch_bounds__(1024) void k0_sort(
    const int* __restrict__ len, int* __restrict__ perm)
{
    __shared__ int wavehist[16][21];
    __shared__ int wavecur [16][21];
    const int tid  = threadIdx.x;
    const int lane = tid & 63;
    const int w    = tid >> 6;

    int cnt = 0;
#pragma unroll 1
    for (int it = 0; it < 32; ++it) {
        int v = len[w * 2048 + it * 64 + lane];
#pragma unroll
        for (int b = 1; b <= 20; ++b) {
            unsigned long long mask = __ballot(v == b);
            if (lane == b - 1) cnt += __popcll(mask);
        }
    }
    if (lane < 20) wavehist[w][lane + 1] = cnt;
    __syncthreads();

    if (tid == 0) {
        int run = 0;
        for (int b = 1; b <= 20; ++b)
            for (int wv = 0; wv < 16; ++wv) {
                int c = wavehist[wv][b];
                wavecur[wv][b] = run;
                run += c;
            }
    }
    __syncthreads();

#pragma unroll 1
    for (int it = 0; it < 32; ++it) {
        int idx = w * 2048 + it * 64 + lane;
        int v = len[idx];
#pragma unroll 1
        for (int b = 1; b <= 20; ++b) {
            unsigned long long mask = __ballot(v == b);
            if (mask) {
                int base = 0;
                if (lane == 0) {
                    base = wavecur[w][b];
                    wavecur[w][b] = base + __popcll(mask);
                }
                base = __shfl(base, 0, 64);
                if (v == b) {
                    int rank = __popcll(mask & ((1ull << lane) - 1ull));
                    perm[base + rank] = idx;
                }
            }
        }
    }
}

// ---------------------------------------------------------------------------
// K1: persistent MFMA micro-GRU, software-pipelined X phase.
// (byte-identical to round 13 — proven, 285.9 µs config)
// ---------------------------------------------------------------------------
__global__ __launch_bounds__(512, 2) void k1_gru_mfma(
    const float* __restrict__ xa, const int* __restrict__ len,
    const int* __restrict__ perm,
    const float* __restrict__ wih, const float* __restrict__ whh,
    const float* __restrict__ bih, const float* __restrict__ bhh,
    short* __restrict__ mh)        // bf16 [M][128]
{
    __shared__ __align__(16) char XbB[3][64 * 256];
    __shared__ __align__(16) char Hb0[64 * 256];
    __shared__ __align__(16) char Hb1[64 * 256];
    __shared__ int pidx[64];
    __shared__ int lens_s[64];

    const int tid = threadIdx.x;
    const int l   = tid & 63;
    const int w   = tid >> 6;     // wave id 0..7 = d-tile
    const int l15 = l & 15;
    const int l4  = l >> 4;

    bf16x8 wf[2][3][4];
#pragma unroll
    for (int s = 0; s < 2; ++s) {
        const float* W = s ? whh : wih;
#pragma unroll
        for (int g = 0; g < 3; ++g) {
            int grow = g * 128 + w * 16 + l15;
#pragma unroll
            for (int kt = 0; kt < 4; ++kt)
                wf[s][g][kt] = cvt8(W + (size_t)grow * 128 + kt * 32 + l4 * 8);
        }
    }

    const int dcol = w * 16 + l15;
    const float brz = bih[dcol]       + bhh[dcol];
    const float bzz = bih[128 + dcol] + bhh[128 + dcol];
    const float bin_= bih[256 + dcol];
    const float bhn_= bhh[256 + dcol];
    const f32x4 bR4 = {brz, brz, brz, brz};
    const f32x4 bZ4 = {bzz, bzz, bzz, bzz};
    const f32x4 bI4 = {bin_, bin_, bin_, bin_};
    const f32x4 bH4 = {bhn_, bhn_, bhn_, bhn_};

    const int sr0 = tid >> 4;          // 0..31
    const int sc8 = (tid & 15) * 8;    // col in elems
    const int lbA = sr0 * 256 + ((sc8 * 2) ^ ((sr0 & 7) << 4));
    const int lbB = (sr0 + 32) * 256 + ((sc8 * 2) ^ (((sr0 + 32) & 7) << 4));

#pragma unroll 1
    for (int pass = 0; pass < 2; ++pass) {
        const int chunk = pass ? (511 - (int)blockIdx.x) : (int)blockIdx.x;

        __syncthreads();   // previous pass fully done with pidx/tiles
        if (tid < 64) {
            int p = perm[chunk * 64 + tid];
            pidx[tid]   = p;
            lens_s[tid] = len[p];
        }
        __syncthreads();

        int lenv[16];
#pragma unroll
        for (int mt = 0; mt < 4; ++mt)
#pragma unroll
            for (int r = 0; r < 4; ++r)
                lenv[mt * 4 + r] = lens_s[mt * 16 + l4 * 4 + r];

        const int Lmax = lens_s[63];   // sorted chunk: last element is max

        const int rA = pidx[sr0];
        const int rB = pidx[sr0 + 32];
        const float* xbA = xa + (size_t)rA * (T_ * D_) + sc8;
        const float* xbB = xa + (size_t)rB * (T_ * D_) + sc8;

        // prologue: stage X0 -> buf0, X1 -> buf1; prefetch X2
        {
            const float4* pA = (const float4*)xbA;
            const float4* pB = (const float4*)xbB;
            *(bf16x8*)(XbB[0] + lbA) = pk8(pA[0], pA[1]);
            *(bf16x8*)(XbB[0] + lbB) = pk8(pB[0], pB[1]);
            const float4* qA = (const float4*)(xbA + D_);
            const float4* qB = (const float4*)(xbB + D_);
            *(bf16x8*)(XbB[1] + lbA) = pk8(qA[0], qA[1]);
            *(bf16x8*)(XbB[1] + lbB) = pk8(qB[0], qB[1]);
        }
        float4 xa0, xa1, xb0v, xb1v;
        {
            const float4* qA = (const float4*)(xbA + 2 * D_);
            const float4* qB = (const float4*)(xbB + 2 * D_);
            xa0 = qA[0]; xa1 = qA[1]; xb0v = qB[0]; xb1v = qB[1];
        }
        lds_barrier();   // X0, X1 visible

        // seed acc with X-phase(0) (bias in C at kt=0); aH = bias (h=0)
        f32x4 aR[4], aZ[4], aI[4], aH[4];
        {
            const char* X0 = XbB[0];
            const int cb0 = l4 * 16;
#pragma unroll
            for (int mt = 0; mt < 4; ++mt) {
                bf16x8 a = t_frag(X0, mt * 16 + l15, cb0);
                aR[mt] = __builtin_amdgcn_mfma_f32_16x16x32_bf16(a, wf[0][0][0], bR4, 0, 0, 0);
                aZ[mt] = __builtin_amdgcn_mfma_f32_16x16x32_bf16(a, wf[0][1][0], bZ4, 0, 0, 0);
                aI[mt] = __builtin_amdgcn_mfma_f32_16x16x32_bf16(a, wf[0][2][0], bI4, 0, 0, 0);
            }
#pragma unroll
            for (int kt = 1; kt < 4; ++kt) {
                const int cb = kt * 64 + l4 * 16;
#pragma unroll
                for (int mt = 0; mt < 4; ++mt) {
                    bf16x8 a = t_frag(X0, mt * 16 + l15, cb);
                    aR[mt] = __builtin_amdgcn_mfma_f32_16x16x32_bf16(a, wf[0][0][kt], aR[mt], 0, 0, 0);
                    aZ[mt] = __builtin_amdgcn_mfma_f32_16x16x32_bf16(a, wf[0][1][kt], aZ[mt], 0, 0, 0);
                    aI[mt] = __builtin_amdgcn_mfma_f32_16x16x32_bf16(a, wf[0][2][kt], aI[mt], 0, 0, 0);
                }
            }
#pragma unroll
            for (int mt = 0; mt < 4; ++mt) aH[mt] = bH4;
        }

        float hm[4][4];
#pragma unroll
        for (int mt = 0; mt < 4; ++mt)
#pragma unroll
            for (int r = 0; r < 4; ++r) hm[mt][r] = 0.f;

        char* Xr_ = XbB[1];
        char* Xw_ = XbB[2];
        char* Xs_ = XbB[0];
        char* Hc = Hb0; char* Hn = Hb1;

#pragma unroll 1
        for (int t = 0; t < Lmax; ++t) {
            // a) stage X(t+2); issue prefetch X(t+3)
            if (t + 2 < Lmax) {
                *(bf16x8*)(Xw_ + lbA) = pk8(xa0, xa1);
                *(bf16x8*)(Xw_ + lbB) = pk8(xb0v, xb1v);
            }
            if (t + 3 < Lmax) {
                const float4* qA = (const float4*)(xbA + (t + 3) * D_);
                const float4* qB = (const float4*)(xbB + (t + 3) * D_);
                xa0 = qA[0]; xa1 = qA[1]; xb0v = qB[0]; xb1v = qB[1];
            }

            // b) H-phase MFMA(t)
            if (t > 0) {
                const int cb0 = l4 * 16;
#pragma unroll
                for (int mt = 0; mt < 4; ++mt) {
                    bf16x8 a = t_frag(Hc, mt * 16 + l15, cb0);
                    aR[mt] = __builtin_amdgcn_mfma_f32_16x16x32_bf16(a, wf[1][0][0], aR[mt], 0, 0, 0);
                    aZ[mt] = __builtin_amdgcn_mfma_f32_16x16x32_bf16(a, wf[1][1][0], aZ[mt], 0, 0, 0);
                    aH[mt] = __builtin_amdgcn_mfma_f32_16x16x32_bf16(a, wf[1][2][0], bH4, 0, 0, 0);
                }
#pragma unroll
                for (int kt = 1; kt < 4; ++kt) {
                    const int cb = kt * 64 + l4 * 16;
#pragma unroll
                    for (int mt = 0; mt < 4; ++mt) {
                        bf16x8 a = t_frag(Hc, mt * 16 + l15, cb);
                        aR[mt] = __builtin_amdgcn_mfma_f32_16x16x32_bf16(a, wf[1][0][kt], aR[mt], 0, 0, 0);
                        aZ[mt] = __builtin_amdgcn_mfma_f32_16x16x32_bf16(a, wf[1][1][kt], aZ[mt], 0, 0, 0);
                        aH[mt] = __builtin_amdgcn_mfma_f32_16x16x32_bf16(a, wf[1][2][kt], aH[mt], 0, 0, 0);
                    }
                }
            }

            // c) per-mt: epilogue(t) -> h-write(t+1) -> re-seed X-phase(t+1)
            const bool more = (t + 1 < Lmax);
#pragma unroll
            for (int mt = 0; mt < 4; ++mt) {
#pragma unroll
                for (int r = 0; r < 4; ++r) {
                    float rr = sigm(aR[mt][r]);
                    float zz = sigm(aZ[mt][r]);
                    float nn = fast_tanh(aI[mt][r] + rr * aH[mt][r]);
                    float hold = hm[mt][r];
                    float hnew = nn + zz * (hold - nn);
                    hm[mt][r] = (t < lenv[mt * 4 + r]) ? hnew : hold;
                }
                if (more) {
#pragma unroll
                    for (int rp = 0; rp < 4; rp += 2) {
                        unsigned pk = cvtpk(hm[mt][rp], hm[mt][rp + 1]);
                        int row0 = mt * 16 + l4 * 4 + rp;
                        int row1 = row0 + 1;
                        *(short*)(Hn + row0 * 256 + ((dcol * 2) ^ ((row0 & 7) << 4))) = (short)(pk & 0xffff);
                        *(short*)(Hn + row1 * 256 + ((dcol * 2) ^ ((row1 & 7) << 4))) = (short)(pk >> 16);
                    }
                    {
                        const int cb0 = l4 * 16;
                        bf16x8 a = t_frag(Xr_, mt * 16 + l15, cb0);
                        aR[mt] = __builtin_amdgcn_mfma_f32_16x16x32_bf16(a, wf[0][0][0], bR4, 0, 0, 0);
                        aZ[mt] = __builtin_amdgcn_mfma_f32_16x16x32_bf16(a, wf[0][1][0], bZ4, 0, 0, 0);
                        aI[mt] = __builtin_amdgcn_mfma_f32_16x16x32_bf16(a, wf[0][2][0], bI4, 0, 0, 0);
                    }
#pragma unroll
                    for (int kt = 1; kt < 4; ++kt) {
                        const int cb = kt * 64 + l4 * 16;
                        bf16x8 a = t_frag(Xr_, mt * 16 + l15, cb);
                        aR[mt] = __builtin_amdgcn_mfma_f32_16x16x32_bf16(a, wf[0][0][kt], aR[mt], 0, 0, 0);
                        aZ[mt] = __builtin_amdgcn_mfma_f32_16x16x32_bf16(a, wf[0][1][kt], aZ[mt], 0, 0, 0);
                        aI[mt] = __builtin_amdgcn_mfma_f32_16x16x32_bf16(a, wf[0][2][kt], aI[mt], 0, 0, 0);
                    }
                }
            }

            // d) barrier; rotate X buffers; swap H buffers
            if (more) {
                lds_barrier();
                char* tmp = Xr_; Xr_ = Xw_; Xw_ = Xs_; Xs_ = tmp;
                char* th = Hc; Hc = Hn; Hn = th;
            }
        }

        // final h -> mh (bf16, scattered by perm)
#pragma unroll
        for (int mt = 0; mt < 4; ++mt) {
#pragma unroll
            for (int r = 0; r < 4; ++r) {
                int m = pidx[mt * 16 + l4 * 4 + r];
                mh[(size_t)m * 128 + dcol] = f2bf(hm[mt][r]);
            }
        }
    }
}

// ---------------------------------------------------------------------------
// K23 (fused k2 + k3a + k3b), SOFTWARE-PIPELINED staging:
// all global loads for K-step kt+1 are issued into raw f32/bf16 registers
// BEFORE kt's MFMAs, stay in flight across lds_barrier() (no vmcnt drain),
// and are converted+ds_written after the barrier. Same math/order as R10.
// ---------------------------------------------------------------------------
__global__ __launch_bounds__(512) void k23_fused(
    const float* __restrict__ A, const float* __restrict__ hidden,
    const float* __restrict__ mi, const short* __restrict__ mh,
    const float* __restrict__ w_in, const float* __restrict__ b_in,
    const float* __restrict__ w_out, const float* __restrict__ b_out,
    const float* __restrict__ b_iah, const float* __restrict__ b_ioh,
    const float* __restrict__ wih, const float* __restrict__ whh,
    const float* __restrict__ bih, const float* __restrict__ bhh,
    float* __restrict__ out)
{
    __shared__ __align__(16) char HIO[64 * 1024];
    __shared__ __align__(16) char INP[64 * 1024];
    __shared__ __align__(16) char STG[24 * 1024];

    const int tid = threadIdx.x;
    const int l = tid & 63, w = tid >> 6;
    const int l15 = l & 15, l4 = l >> 4;
    const int wr = w >> 1, wc = w & 1;
    const int b  = blockIdx.x;
    const int m0 = b * 128;

    char* As  = STG;
    char* Bs  = STG + 8 * 1024;
    const int srow = tid >> 2, sc4 = tid & 3;
    const int brow = tid >> 1, bh  = tid & 1;

    // ================= Phase 1: k2 -> hioT_lds =================
    {
        float bj[8];
#pragma unroll
        for (int cf = 0; cf < 8; ++cf) {
            int j = wc * 128 + cf * 16 + l15;
            bj[cf] = (j < 128) ? b_in[j] : b_out[j - 128];
        }
        f32x4 acc[2][8];
#pragma unroll
        for (int rf = 0; rf < 2; ++rf)
#pragma unroll
            for (int cf = 0; cf < 8; ++cf) acc[rf][cf] = (f32x4){0.f,0.f,0.f,0.f};

        // raw prefetch regs
        float4 ra0, ra1; bf16x8 rah;   // A-side (mi f32 or mh bf16)
        float4 rb0, rb1, rb2, rb3;     // B-side (W f32)

        // preload kt=0
        {
            const float* asrc = mi + (size_t)(m0 + srow) * 128 + sc4 * 8;
            ra0 = ((const float4*)asrc)[0]; ra1 = ((const float4*)asrc)[1];
            const float* wsrc = (brow < 128)
                ? (w_in  + (size_t)brow * 256 + bh * 16)
                : (w_out + (size_t)(brow - 128) * 256 + bh * 16);
            rb0 = ((const float4*)wsrc)[0]; rb1 = ((const float4*)wsrc)[1];
            rb2 = ((const float4*)wsrc)[2]; rb3 = ((const float4*)wsrc)[3];
        }

#pragma unroll 1
        for (int kt = 0; kt < 8; ++kt) {
            // write staged kt (vmcnt wait lands here)
            *(bf16x8*)(As + SLADDR(srow, sc4)) = (kt < 4) ? pk8(ra0, ra1) : rah;
            *(bf16x8*)(Bs + SLADDR(brow, bh * 2    )) = pk8(rb0, rb1);
            *(bf16x8*)(Bs + SLADDR(brow, bh * 2 + 1)) = pk8(rb2, rb3);

            // issue loads for kt+1 (in flight across both barriers)
            if (kt + 1 < 8) {
                const int k2 = kt + 1;
                if (k2 < 4) {
                    const float* asrc = mi + (size_t)(m0 + srow) * 128 + k2 * 32 + sc4 * 8;
                    ra0 = ((const float4*)asrc)[0]; ra1 = ((const float4*)asrc)[1];
                } else {
                    rah = *(const bf16x8*)(mh + (size_t)(m0 + srow) * 128 + (k2 - 4) * 32 + sc4 * 8);
                }
                const float* wsrc = (brow < 128)
                    ? (w_in  + (size_t)brow * 256 + k2 * 32 + bh * 16)
                    : (w_out + (size_t)(brow - 128) * 256 + k2 * 32 + bh * 16);
                rb0 = ((const float4*)wsrc)[0]; rb1 = ((const float4*)wsrc)[1];
                rb2 = ((const float4*)wsrc)[2]; rb3 = ((const float4*)wsrc)[3];
            }
            lds_barrier();

            bf16x8 af[2], bfr[8];
#pragma unroll
            for (int rf = 0; rf < 2; ++rf)
                af[rf] = *(const bf16x8*)(As + SLADDR(wr * 32 + rf * 16 + l15, l4));
#pragma unroll
            for (int cf = 0; cf < 8; ++cf)
                bfr[cf] = *(const bf16x8*)(Bs + SLADDR(wc * 128 + cf * 16 + l15, l4));
#pragma unroll
            for (int rf = 0; rf < 2; ++rf)
#pragma unroll
                for (int cf = 0; cf < 8; ++cf)
                    acc[rf][cf] = __builtin_amdgcn_mfma_f32_16x16x32_bf16(af[rf], bfr[cf], acc[rf][cf], 0, 0, 0);
            lds_barrier();
        }

#pragma unroll
        for (int rf = 0; rf < 2; ++rf)
#pragma unroll
            for (int cf = 0; cf < 8; ++cf) {
                int j  = wc * 128 + cf * 16 + l15;
                int e0 = wr * 32 + rf * 16 + l4 * 4;
                s16x4 s;
#pragma unroll
                for (int r = 0; r < 4; ++r) s[r] = f2bf(acc[rf][cf][r] + bj[cf]);
                *(s16x4*)(HIO + j * 256 + ((e0 * 2) ^ ((j & 7) << 4))) = s;
            }
        lds_barrier();
    }

    // ================= Phase 2: k3a -> inputs_lds =================
    {
        char* As0 = STG;
        char* As1 = STG + 8 * 1024;
        float bj[8];
#pragma unroll
        for (int cf = 0; cf < 8; ++cf) {
            int j = wc * 128 + cf * 16 + l15;
            bj[cf] = (j < 128) ? b_iah[j] : b_ioh[j - 128];
        }
        f32x4 acc[2][8];
#pragma unroll
        for (int rf = 0; rf < 2; ++rf)
#pragma unroll
            for (int cf = 0; cf < 8; ++cf) acc[rf][cf] = (f32x4){0.f,0.f,0.f,0.f};

        const float* Ab = A + (size_t)b * 128 * 256;
        float4 ra0, ra1, ra2, ra3;     // A-slices (As0: ra0/1, As1: ra2/3)
        {
            const float* s0 = Ab + (size_t)srow * 256 +       sc4 * 8;
            const float* s1 = Ab + (size_t)srow * 256 + 128 + sc4 * 8;
            ra0 = ((const float4*)s0)[0]; ra1 = ((const float4*)s0)[1];
            ra2 = ((const float4*)s1)[0]; ra3 = ((const float4*)s1)[1];
        }

#pragma unroll 1
        for (int kt = 0; kt < 4; ++kt) {
            *(bf16x8*)(As0 + SLADDR(srow, sc4)) = pk8(ra0, ra1);
            *(bf16x8*)(As1 + SLADDR(srow, sc4)) = pk8(ra2, ra3);
            if (kt + 1 < 4) {
                const int k2 = kt + 1;
                const float* s0 = Ab + (size_t)srow * 256 +       k2 * 32 + sc4 * 8;
                const float* s1 = Ab + (size_t)srow * 256 + 128 + k2 * 32 + sc4 * 8;
                ra0 = ((const float4*)s0)[0]; ra1 = ((const float4*)s0)[1];
                ra2 = ((const float4*)s1)[0]; ra3 = ((const float4*)s1)[1];
            }
            lds_barrier();

            const char* Asel = wc ? As1 : As0;
            bf16x8 af[2], bfr[8];
#pragma unroll
            for (int rf = 0; rf < 2; ++rf)
                af[rf] = *(const bf16x8*)(Asel + SLADDR(wr * 32 + rf * 16 + l15, l4));
#pragma unroll
            for (int cf = 0; cf < 8; ++cf)
                bfr[cf] = t_frag(HIO, wc * 128 + cf * 16 + l15, kt * 64 + l4 * 16);
#pragma unroll
            for (int rf = 0; rf < 2; ++rf)
#pragma unroll
                for (int cf = 0; cf < 8; ++cf)
                    acc[rf][cf] = __builtin_amdgcn_mfma_f32_16x16x32_bf16(af[rf], bfr[cf], acc[rf][cf], 0, 0, 0);
            lds_barrier();
        }

#pragma unroll
        for (int rf = 0; rf < 2; ++rf)
#pragma unroll
            for (int cf = 0; cf < 8; ++cf) {
                int j = wc * 128 + cf * 16 + l15;
#pragma unroll
                for (int r = 0; r < 4; ++r) {
                    int n = wr * 32 + rf * 16 + l4 * 4 + r;
                    *(short*)(INP + n * 512 + ((j * 2) ^ ((n & 7) << 4))) = f2bf(acc[rf][cf][r] + bj[cf]);
                }
            }
        lds_barrier();
    }

    // ================= Phase 3: k3b -> out =================
    {
        char* Bs3 = STG;
        char* HID = HIO;

        float br[4], bz[4], bi[4], bh_[4];
#pragma unroll
        for (int p = 0; p < 4; ++p) {
            int d = (wc * 4 + p) * 16 + l15;
            br[p] = bih[d]       + bhh[d];
            bz[p] = bih[128 + d] + bhh[128 + d];
            bi[p] = bih[256 + d];
            bh_[p]= bhh[256 + d];
        }
        f32x4 aR[2][4], aZ[2][4], aI[2][4], aH[2][4];
#pragma unroll
        for (int rf = 0; rf < 2; ++rf)
#pragma unroll
            for (int p = 0; p < 4; ++p) {
                aR[rf][p] = (f32x4){0.f,0.f,0.f,0.f};
                aZ[rf][p] = (f32x4){0.f,0.f,0.f,0.f};
                aI[rf][p] = (f32x4){0.f,0.f,0.f,0.f};
                aH[rf][p] = (f32x4){0.f,0.f,0.f,0.f};
            }

        // raw prefetch regs: 3 staging rows of W (6 float4) + hidden (2 float4)
        float4 rb[6];
        float4 rh0, rh1;
        {
#pragma unroll
            for (int i = 0; i < 3; ++i) {
                int c = tid + 512 * i;
                int row = c >> 2, ch = c & 3;
                const float* wsrc = wih + (size_t)row * 256 + ch * 8;
                rb[2*i]   = ((const float4*)wsrc)[0];
                rb[2*i+1] = ((const float4*)wsrc)[1];
            }
        }

#pragma unroll 1
        for (int kt = 0; kt < 12; ++kt) {
            // write staged kt
            if (kt >= 8) {
                *(bf16x8*)(HID + SLADDR(srow, sc4)) = pk8(rh0, rh1);
            }
#pragma unroll
            for (int i = 0; i < 3; ++i) {
                int c = tid + 512 * i;
                int row = c >> 2, ch = c & 3;
                *(bf16x8*)(Bs3 + SLADDR(row, ch)) = pk8(rb[2*i], rb[2*i+1]);
            }
            // issue loads for kt+1
            if (kt + 1 < 12) {
                const int k2 = kt + 1;
#pragma unroll
                for (int i = 0; i < 3; ++i) {
                    int c = tid + 512 * i;
                    int row = c >> 2, ch = c & 3;
                    const float* wsrc = (k2 < 8)
                        ? (wih + (size_t)row * 256 + k2 * 32 + ch * 8)
                        : (whh + (size_t)row * 128 + (k2 - 8) * 32 + ch * 8);
                    rb[2*i]   = ((const float4*)wsrc)[0];
                    rb[2*i+1] = ((const float4*)wsrc)[1];
                }
                if (k2 >= 8) {
                    const float* src = hidden + (size_t)(m0 + srow) * 128 + (k2 - 8) * 32 + sc4 * 8;
                    rh0 = ((const float4*)src)[0]; rh1 = ((const float4*)src)[1];
                }
            }
            lds_barrier();

            bf16x8 a0, a1;
            if (kt < 8) {
                const int cb = kt * 64 + l4 * 16;
                a0 = t_frag512(INP, wr * 32 +      l15, cb);
                a1 = t_frag512(INP, wr * 32 + 16 + l15, cb);
            } else {
                a0 = *(const bf16x8*)(HID + SLADDR(wr * 32 +      l15, l4));
                a1 = *(const bf16x8*)(HID + SLADDR(wr * 32 + 16 + l15, l4));
            }
#pragma unroll
            for (int p = 0; p < 4; ++p) {
                int jb = (wc * 4 + p) * 16 + l15;
                bf16x8 bR = *(const bf16x8*)(Bs3 + SLADDR(      jb, l4));
                bf16x8 bZ = *(const bf16x8*)(Bs3 + SLADDR(128 + jb, l4));
                bf16x8 bN = *(const bf16x8*)(Bs3 + SLADDR(256 + jb, l4));
                aR[0][p] = __builtin_amdgcn_mfma_f32_16x16x32_bf16(a0, bR, aR[0][p], 0, 0, 0);
                aR[1][p] = __builtin_amdgcn_mfma_f32_16x16x32_bf16(a1, bR, aR[1][p], 0, 0, 0);
                aZ[0][p] = __builtin_amdgcn_mfma_f32_16x16x32_bf16(a0, bZ, aZ[0][p], 0, 0, 0);
                aZ[1][p] = __builtin_amdgcn_mfma_f32_16x16x32_bf16(a1, bZ, aZ[1][p], 0, 0, 0);
                if (kt < 8) {
                    aI[0][p] = __builtin_amdgcn_mfma_f32_16x16x32_bf16(a0, bN, aI[0][p], 0, 0, 0);
                    aI[1][p] = __builtin_amdgcn_mfma_f32_16x16x32_bf16(a1, bN, aI[1][p], 0, 0, 0);
                } else {
                    aH[0][p] = __builtin_amdgcn_mfma_f32_16x16x32_bf16(a0, bN, aH[0][p], 0, 0, 0);
                    aH[1][p] = __builtin_amdgcn_mfma_f32_16x16x32_bf16(a1, bN, aH[1][p], 0, 0, 0);
                }
            }
            lds_barrier();
        }

#pragma unroll
        for (int rf = 0; rf < 2; ++rf)
#pragma unroll
            for (int p = 0; p < 4; ++p) {
                int d = (wc * 4 + p) * 16 + l15;
#pragma unroll
                for (int r = 0; r < 4; ++r) {
                    int m = m0 + wr * 32 + rf * 16 + l4 * 4 + r;
                    float hv = hidden[(size_t)m * 128 + d];
                    float rg = sigm(aR[rf][p][r] + br[p]);
                    float zg = sigm(aZ[rf][p][r] + bz[p]);
                    float ng = fast_tanh(aI[rf][p][r] + bi[p] + rg * (aH[rf][p][r] + bh_[p]));
                    out[(size_t)m * 128 + d] = (1.f - zg) * hv + zg * ng;
                }
            }
    }
}

// ---------------------------------------------------------------------------
extern "C" void kernel_launch(void* const* d_in, const int* in_sizes, int n_in,
                              void* d_out, int out_size, void* d_ws, size_t ws_size,
                              hipStream_t stream) {
    const float* A     = (const float*)d_in[0];
    const float* hidden= (const float*)d_in[1];
    const float* mi    = (const float*)d_in[2];
    const float* xa    = (const float*)d_in[3];
    const int*   len   = (const int*)  d_in[4];
    const float* gwih  = (const float*)d_in[5];
    const float* gwhh  = (const float*)d_in[6];
    const float* gbih  = (const float*)d_in[7];
    const float* gbhh  = (const float*)d_in[8];
    const float* wih   = (const float*)d_in[9];
    const float* whh   = (const float*)d_in[10];
    const float* bih   = (const float*)d_in[11];
    const float* bhh   = (const float*)d_in[12];
    const float* biah  = (const float*)d_in[13];
    const float* bioh  = (const float*)d_in[14];
    const float* w_in  = (const float*)d_in[15];
    const float* b_in  = (const float*)d_in[16];
    const float* w_out = (const float*)d_in[17];
    const float* b_out = (const float*)d_in[18];

    float* out = (float*)d_out;
    // ws layout (8.5 MB):
    //   [0, 8.39 MB):      mh bf16 [M][128]   (k1 -> k23)
    //   [8.39 MB, +128KB): perm int [M]       (k0 -> k1)
    short* mh   = (short*)d_ws;
    int*   perm = (int*)((char*)d_ws + (size_t)M_ * D_ * 2);

    k0_sort    <<<1,      1024, 0, stream>>>(len, perm);
    k1_gru_mfma<<<256,     512, 0, stream>>>(xa, len, perm, gwih, gwhh, gbih, gbhh, mh);
    k23_fused  <<<B_,      512, 0, stream>>>(A, hidden, mi, mh,
                                             w_in, b_in, w_out, b_out,
                                             biah, bioh, wih, whh, bih, bhh, out);
}

// Round 16
// 278.693 us; speedup vs baseline: 1.2657x; 1.0011x over previous
//
#include <hip/hip_runtime.h>
#include <math.h>

#define B_ 256
#define E_ 128
#define N_ 128
#define T_ 20
#define D_ 128
#define M_ (B_*E_)   // 32768 sequences

typedef __attribute__((ext_vector_type(8))) short bf16x8;
typedef __attribute__((ext_vector_type(4))) short s16x4;
typedef __attribute__((ext_vector_type(4))) float f32x4;
typedef __attribute__((ext_vector_type(4))) unsigned u32x4;

__device__ __forceinline__ float sigm(float x) { return 1.0f / (1.0f + __expf(-x)); }
__device__ __forceinline__ float fast_tanh(float x) {
    float e = __expf(2.f * x);
    return 1.f - 2.f / (e + 1.f);
}
__device__ __forceinline__ short f2bf(float f) {   // RNE float->bf16 (scalar)
    unsigned u = __builtin_bit_cast(unsigned, f);
    u += 0x7fffu + ((u >> 16) & 1u);
    return (short)(u >> 16);
}
// HW packed convert: 2 f32 -> 2 bf16 in one instruction (RNE).
__device__ __forceinline__ unsigned cvtpk(float lo, float hi) {
    unsigned r;
    asm("v_cvt_pk_bf16_f32 %0, %1, %2" : "=v"(r) : "v"(lo), "v"(hi));
    return r;
}
__device__ __forceinline__ bf16x8 pk8(float4 a, float4 b) {
    u32x4 u = { cvtpk(a.x,a.y), cvtpk(a.z,a.w), cvtpk(b.x,b.y), cvtpk(b.z,b.w) };
    return __builtin_bit_cast(bf16x8, u);
}
__device__ __forceinline__ bf16x8 cvt8(const float* __restrict__ p) {
    float4 u = *(const float4*)p;
    float4 v = *(const float4*)(p + 4);
    return pk8(u, v);
}

// [rows][32k] bf16 slice, 64 B/row; chunk-XOR swizzle.
#define SLADDR(row, chunk) ((row) * 64 + ((((chunk) ^ ((row) >> 1)) & 3) << 4))

// [rows][128 cols bf16] tile, 256 B/row, byte-XOR swizzle.
__device__ __forceinline__ bf16x8 t_frag(const char* base, int row, int cb) {
    return *(const bf16x8*)(base + row * 256 + (cb ^ ((row & 7) << 4)));
}
// [rows][256 cols bf16] tile, 512 B/row, byte-XOR swizzle.
__device__ __forceinline__ bf16x8 t_frag512(const char* base, int row, int cb) {
    return *(const bf16x8*)(base + row * 512 + (cb ^ ((row & 7) << 4)));
}

// LDS-only barrier: drain LDS ops, sync, but DON'T drain vmcnt.
__device__ __forceinline__ void lds_barrier() {
    asm volatile("s_waitcnt lgkmcnt(0)" ::: "memory");
    __builtin_amdgcn_s_barrier();
    asm volatile("" ::: "memory");
}

// ---------------------------------------------------------------------------
// K0: deterministic counting sort of sequence indices by len (bins 1..20).
// Bin-major fill => within each 64-chunk lens are NON-DECREASING (max = last).
// ---------------------------------------------------------------------------
__global__ __launch_bounds__(1024) void k0_sort(
    const int* __restrict__ len, int* __restrict__ perm)
{
    __shared__ int wavehist[16][21];
    __shared__ int wavecur [16][21];
    const int tid  = threadIdx.x;
    const int lane = tid & 63;
    const int w    = tid >> 6;

    int cnt = 0;
#pragma unroll 1
    for (int it = 0; it < 32; ++it) {
        int v = len[w * 2048 + it * 64 + lane];
#pragma unroll
        for (int b = 1; b <= 20; ++b) {
            unsigned long long mask = __ballot(v == b);
            if (lane == b - 1) cnt += __popcll(mask);
        }
    }
    if (lane < 20) wavehist[w][lane + 1] = cnt;
    __syncthreads();

    if (tid == 0) {
        int run = 0;
        for (int b = 1; b <= 20; ++b)
            for (int wv = 0; wv < 16; ++wv) {
                int c = wavehist[wv][b];
                wavecur[wv][b] = run;
                run += c;
            }
    }
    __syncthreads();

#pragma unroll 1
    for (int it = 0; it < 32; ++it) {
        int idx = w * 2048 + it * 64 + lane;
        int v = len[idx];
#pragma unroll 1
        for (int b = 1; b <= 20; ++b) {
            unsigned long long mask = __ballot(v == b);
            if (mask) {
                int base = 0;
                if (lane == 0) {
                    base = wavecur[w][b];
                    wavecur[w][b] = base + __popcll(mask);
                }
                base = __shfl(base, 0, 64);
                if (v == b) {
                    int rank = __popcll(mask & ((1ull << lane) - 1ull));
                    perm[base + rank] = idx;
                }
            }
        }
    }
}

// ---------------------------------------------------------------------------
// K1: persistent MFMA micro-GRU, software-pipelined X phase.
// (byte-identical to round 13/14 — proven)
// ---------------------------------------------------------------------------
__global__ __launch_bounds__(512, 2) void k1_gru_mfma(
    const float* __restrict__ xa, const int* __restrict__ len,
    const int* __restrict__ perm,
    const float* __restrict__ wih, const float* __restrict__ whh,
    const float* __restrict__ bih, const float* __restrict__ bhh,
    short* __restrict__ mh)        // bf16 [M][128]
{
    __shared__ __align__(16) char XbB[3][64 * 256];
    __shared__ __align__(16) char Hb0[64 * 256];
    __shared__ __align__(16) char Hb1[64 * 256];
    __shared__ int pidx[64];
    __shared__ int lens_s[64];

    const int tid = threadIdx.x;
    const int l   = tid & 63;
    const int w   = tid >> 6;     // wave id 0..7 = d-tile
    const int l15 = l & 15;
    const int l4  = l >> 4;

    bf16x8 wf[2][3][4];
#pragma unroll
    for (int s = 0; s < 2; ++s) {
        const float* W = s ? whh : wih;
#pragma unroll
        for (int g = 0; g < 3; ++g) {
            int grow = g * 128 + w * 16 + l15;
#pragma unroll
            for (int kt = 0; kt < 4; ++kt)
                wf[s][g][kt] = cvt8(W + (size_t)grow * 128 + kt * 32 + l4 * 8);
        }
    }

    const int dcol = w * 16 + l15;
    const float brz = bih[dcol]       + bhh[dcol];
    const float bzz = bih[128 + dcol] + bhh[128 + dcol];
    const float bin_= bih[256 + dcol];
    const float bhn_= bhh[256 + dcol];
    const f32x4 bR4 = {brz, brz, brz, brz};
    const f32x4 bZ4 = {bzz, bzz, bzz, bzz};
    const f32x4 bI4 = {bin_, bin_, bin_, bin_};
    const f32x4 bH4 = {bhn_, bhn_, bhn_, bhn_};

    const int sr0 = tid >> 4;          // 0..31
    const int sc8 = (tid & 15) * 8;    // col in elems
    const int lbA = sr0 * 256 + ((sc8 * 2) ^ ((sr0 & 7) << 4));
    const int lbB = (sr0 + 32) * 256 + ((sc8 * 2) ^ (((sr0 + 32) & 7) << 4));

#pragma unroll 1
    for (int pass = 0; pass < 2; ++pass) {
        const int chunk = pass ? (511 - (int)blockIdx.x) : (int)blockIdx.x;

        __syncthreads();   // previous pass fully done with pidx/tiles
        if (tid < 64) {
            int p = perm[chunk * 64 + tid];
            pidx[tid]   = p;
            lens_s[tid] = len[p];
        }
        __syncthreads();

        int lenv[16];
#pragma unroll
        for (int mt = 0; mt < 4; ++mt)
#pragma unroll
            for (int r = 0; r < 4; ++r)
                lenv[mt * 4 + r] = lens_s[mt * 16 + l4 * 4 + r];

        const int Lmax = lens_s[63];   // sorted chunk: last element is max

        const int rA = pidx[sr0];
        const int rB = pidx[sr0 + 32];
        const float* xbA = xa + (size_t)rA * (T_ * D_) + sc8;
        const float* xbB = xa + (size_t)rB * (T_ * D_) + sc8;

        // prologue: stage X0 -> buf0, X1 -> buf1; prefetch X2
        {
            const float4* pA = (const float4*)xbA;
            const float4* pB = (const float4*)xbB;
            *(bf16x8*)(XbB[0] + lbA) = pk8(pA[0], pA[1]);
            *(bf16x8*)(XbB[0] + lbB) = pk8(pB[0], pB[1]);
            const float4* qA = (const float4*)(xbA + D_);
            const float4* qB = (const float4*)(xbB + D_);
            *(bf16x8*)(XbB[1] + lbA) = pk8(qA[0], qA[1]);
            *(bf16x8*)(XbB[1] + lbB) = pk8(qB[0], qB[1]);
        }
        float4 xa0, xa1, xb0v, xb1v;
        {
            const float4* qA = (const float4*)(xbA + 2 * D_);
            const float4* qB = (const float4*)(xbB + 2 * D_);
            xa0 = qA[0]; xa1 = qA[1]; xb0v = qB[0]; xb1v = qB[1];
        }
        lds_barrier();   // X0, X1 visible

        // seed acc with X-phase(0) (bias in C at kt=0); aH = bias (h=0)
        f32x4 aR[4], aZ[4], aI[4], aH[4];
        {
            const char* X0 = XbB[0];
            const int cb0 = l4 * 16;
#pragma unroll
            for (int mt = 0; mt < 4; ++mt) {
                bf16x8 a = t_frag(X0, mt * 16 + l15, cb0);
                aR[mt] = __builtin_amdgcn_mfma_f32_16x16x32_bf16(a, wf[0][0][0], bR4, 0, 0, 0);
                aZ[mt] = __builtin_amdgcn_mfma_f32_16x16x32_bf16(a, wf[0][1][0], bZ4, 0, 0, 0);
                aI[mt] = __builtin_amdgcn_mfma_f32_16x16x32_bf16(a, wf[0][2][0], bI4, 0, 0, 0);
            }
#pragma unroll
            for (int kt = 1; kt < 4; ++kt) {
                const int cb = kt * 64 + l4 * 16;
#pragma unroll
                for (int mt = 0; mt < 4; ++mt) {
                    bf16x8 a = t_frag(X0, mt * 16 + l15, cb);
                    aR[mt] = __builtin_amdgcn_mfma_f32_16x16x32_bf16(a, wf[0][0][kt], aR[mt], 0, 0, 0);
                    aZ[mt] = __builtin_amdgcn_mfma_f32_16x16x32_bf16(a, wf[0][1][kt], aZ[mt], 0, 0, 0);
                    aI[mt] = __builtin_amdgcn_mfma_f32_16x16x32_bf16(a, wf[0][2][kt], aI[mt], 0, 0, 0);
                }
            }
#pragma unroll
            for (int mt = 0; mt < 4; ++mt) aH[mt] = bH4;
        }

        float hm[4][4];
#pragma unroll
        for (int mt = 0; mt < 4; ++mt)
#pragma unroll
            for (int r = 0; r < 4; ++r) hm[mt][r] = 0.f;

        char* Xr_ = XbB[1];
        char* Xw_ = XbB[2];
        char* Xs_ = XbB[0];
        char* Hc = Hb0; char* Hn = Hb1;

#pragma unroll 1
        for (int t = 0; t < Lmax; ++t) {
            // a) stage X(t+2); issue prefetch X(t+3)
            if (t + 2 < Lmax) {
                *(bf16x8*)(Xw_ + lbA) = pk8(xa0, xa1);
                *(bf16x8*)(Xw_ + lbB) = pk8(xb0v, xb1v);
            }
            if (t + 3 < Lmax) {
                const float4* qA = (const float4*)(xbA + (t + 3) * D_);
                const float4* qB = (const float4*)(xbB + (t + 3) * D_);
                xa0 = qA[0]; xa1 = qA[1]; xb0v = qB[0]; xb1v = qB[1];
            }

            // b) H-phase MFMA(t)
            if (t > 0) {
                const int cb0 = l4 * 16;
#pragma unroll
                for (int mt = 0; mt < 4; ++mt) {
                    bf16x8 a = t_frag(Hc, mt * 16 + l15, cb0);
                    aR[mt] = __builtin_amdgcn_mfma_f32_16x16x32_bf16(a, wf[1][0][0], aR[mt], 0, 0, 0);
                    aZ[mt] = __builtin_amdgcn_mfma_f32_16x16x32_bf16(a, wf[1][1][0], aZ[mt], 0, 0, 0);
                    aH[mt] = __builtin_amdgcn_mfma_f32_16x16x32_bf16(a, wf[1][2][0], bH4, 0, 0, 0);
                }
#pragma unroll
                for (int kt = 1; kt < 4; ++kt) {
                    const int cb = kt * 64 + l4 * 16;
#pragma unroll
                    for (int mt = 0; mt < 4; ++mt) {
                        bf16x8 a = t_frag(Hc, mt * 16 + l15, cb);
                        aR[mt] = __builtin_amdgcn_mfma_f32_16x16x32_bf16(a, wf[1][0][kt], aR[mt], 0, 0, 0);
                        aZ[mt] = __builtin_amdgcn_mfma_f32_16x16x32_bf16(a, wf[1][1][kt], aZ[mt], 0, 0, 0);
                        aH[mt] = __builtin_amdgcn_mfma_f32_16x16x32_bf16(a, wf[1][2][kt], aH[mt], 0, 0, 0);
                    }
                }
            }

            // c) per-mt: epilogue(t) -> h-write(t+1) -> re-seed X-phase(t+1)
            const bool more = (t + 1 < Lmax);
#pragma unroll
            for (int mt = 0; mt < 4; ++mt) {
#pragma unroll
                for (int r = 0; r < 4; ++r) {
                    float rr = sigm(aR[mt][r]);
                    float zz = sigm(aZ[mt][r]);
                    float nn = fast_tanh(aI[mt][r] + rr * aH[mt][r]);
                    float hold = hm[mt][r];
                    float hnew = nn + zz * (hold - nn);
                    hm[mt][r] = (t < lenv[mt * 4 + r]) ? hnew : hold;
                }
                if (more) {
#pragma unroll
                    for (int rp = 0; rp < 4; rp += 2) {
                        unsigned pk = cvtpk(hm[mt][rp], hm[mt][rp + 1]);
                        int row0 = mt * 16 + l4 * 4 + rp;
                        int row1 = row0 + 1;
                        *(short*)(Hn + row0 * 256 + ((dcol * 2) ^ ((row0 & 7) << 4))) = (short)(pk & 0xffff);
                        *(short*)(Hn + row1 * 256 + ((dcol * 2) ^ ((row1 & 7) << 4))) = (short)(pk >> 16);
                    }
                    {
                        const int cb0 = l4 * 16;
                        bf16x8 a = t_frag(Xr_, mt * 16 + l15, cb0);
                        aR[mt] = __builtin_amdgcn_mfma_f32_16x16x32_bf16(a, wf[0][0][0], bR4, 0, 0, 0);
                        aZ[mt] = __builtin_amdgcn_mfma_f32_16x16x32_bf16(a, wf[0][1][0], bZ4, 0, 0, 0);
                        aI[mt] = __builtin_amdgcn_mfma_f32_16x16x32_bf16(a, wf[0][2][0], bI4, 0, 0, 0);
                    }
#pragma unroll
                    for (int kt = 1; kt < 4; ++kt) {
                        const int cb = kt * 64 + l4 * 16;
                        bf16x8 a = t_frag(Xr_, mt * 16 + l15, cb);
                        aR[mt] = __builtin_amdgcn_mfma_f32_16x16x32_bf16(a, wf[0][0][kt], aR[mt], 0, 0, 0);
                        aZ[mt] = __builtin_amdgcn_mfma_f32_16x16x32_bf16(a, wf[0][1][kt], aZ[mt], 0, 0, 0);
                        aI[mt] = __builtin_amdgcn_mfma_f32_16x16x32_bf16(a, wf[0][2][kt], aI[mt], 0, 0, 0);
                    }
                }
            }

            // d) barrier; rotate X buffers; swap H buffers
            if (more) {
                lds_barrier();
                char* tmp = Xr_; Xr_ = Xw_; Xw_ = Xs_; Xs_ = tmp;
                char* th = Hc; Hc = Hn; Hn = th;
            }
        }

        // final h -> mh (bf16, scattered by perm)
#pragma unroll
        for (int mt = 0; mt < 4; ++mt) {
#pragma unroll
            for (int r = 0; r < 4; ++r) {
                int m = pidx[mt * 16 + l4 * 4 + r];
                mh[(size_t)m * 128 + dcol] = f2bf(hm[mt][r]);
            }
        }
    }
}

// ---------------------------------------------------------------------------
// K23 (fused k2 + k3a + k3b), pipelined staging + DOUBLE-BUFFERED staging
// regions carved from dead LDS (ternary buffer select — hipcc rejects arrays
// of generic pointers initialized from LDS objects): ONE lds_barrier/K-step.
//   P1 staging: {STG, HIO[0:24K]}   (HIO dead until its result write)
//   P2 staging: {STG, INP[0:16K]}   (INP dead until its result write)
//   P3 staging: W -> {STG, HIO[0:24K]}, hidden -> HIO[32K/40K] halves
// ---------------------------------------------------------------------------
__global__ __launch_bounds__(512) void k23_fused(
    const float* __restrict__ A, const float* __restrict__ hidden,
    const float* __restrict__ mi, const short* __restrict__ mh,
    const float* __restrict__ w_in, const float* __restrict__ b_in,
    const float* __restrict__ w_out, const float* __restrict__ b_out,
    const float* __restrict__ b_iah, const float* __restrict__ b_ioh,
    const float* __restrict__ wih, const float* __restrict__ whh,
    const float* __restrict__ bih, const float* __restrict__ bhh,
    float* __restrict__ out)
{
    __shared__ __align__(16) char HIO[64 * 1024];
    __shared__ __align__(16) char INP[64 * 1024];
    __shared__ __align__(16) char STG[24 * 1024];

    const int tid = threadIdx.x;
    const int l = tid & 63, w = tid >> 6;
    const int l15 = l & 15, l4 = l >> 4;
    const int wr = w >> 1, wc = w & 1;
    const int b  = blockIdx.x;
    const int m0 = b * 128;

    char* const pSTG = STG;   // generic-AS copies (avoid static-init addrspacecast)
    char* const pHIO = HIO;
    char* const pINP = INP;

    const int srow = tid >> 2, sc4 = tid & 3;
    const int brow = tid >> 1, bh  = tid & 1;

    // ================= Phase 1: k2 -> hioT_lds =================
    {
        float bj[8];
#pragma unroll
        for (int cf = 0; cf < 8; ++cf) {
            int j = wc * 128 + cf * 16 + l15;
            bj[cf] = (j < 128) ? b_in[j] : b_out[j - 128];
        }
        f32x4 acc[2][8];
#pragma unroll
        for (int rf = 0; rf < 2; ++rf)
#pragma unroll
            for (int cf = 0; cf < 8; ++cf) acc[rf][cf] = (f32x4){0.f,0.f,0.f,0.f};

        float4 ra0, ra1; bf16x8 rah;
        float4 rb0, rb1, rb2, rb3;
        {
            const float* asrc = mi + (size_t)(m0 + srow) * 128 + sc4 * 8;
            ra0 = ((const float4*)asrc)[0]; ra1 = ((const float4*)asrc)[1];
            const float* wsrc = (brow < 128)
                ? (w_in  + (size_t)brow * 256 + bh * 16)
                : (w_out + (size_t)(brow - 128) * 256 + bh * 16);
            rb0 = ((const float4*)wsrc)[0]; rb1 = ((const float4*)wsrc)[1];
            rb2 = ((const float4*)wsrc)[2]; rb3 = ((const float4*)wsrc)[3];
        }

#pragma unroll 1
        for (int kt = 0; kt < 8; ++kt) {
            char* Asb = (kt & 1) ? pHIO            : pSTG;
            char* Bsb = (kt & 1) ? pHIO + 8 * 1024 : pSTG + 8 * 1024;
            *(bf16x8*)(Asb + SLADDR(srow, sc4)) = (kt < 4) ? pk8(ra0, ra1) : rah;
            *(bf16x8*)(Bsb + SLADDR(brow, bh * 2    )) = pk8(rb0, rb1);
            *(bf16x8*)(Bsb + SLADDR(brow, bh * 2 + 1)) = pk8(rb2, rb3);

            if (kt + 1 < 8) {
                const int k2 = kt + 1;
                if (k2 < 4) {
                    const float* asrc = mi + (size_t)(m0 + srow) * 128 + k2 * 32 + sc4 * 8;
                    ra0 = ((const float4*)asrc)[0]; ra1 = ((const float4*)asrc)[1];
                } else {
                    rah = *(const bf16x8*)(mh + (size_t)(m0 + srow) * 128 + (k2 - 4) * 32 + sc4 * 8);
                }
                const float* wsrc = (brow < 128)
                    ? (w_in  + (size_t)brow * 256 + k2 * 32 + bh * 16)
                    : (w_out + (size_t)(brow - 128) * 256 + k2 * 32 + bh * 16);
                rb0 = ((const float4*)wsrc)[0]; rb1 = ((const float4*)wsrc)[1];
                rb2 = ((const float4*)wsrc)[2]; rb3 = ((const float4*)wsrc)[3];
            }
            lds_barrier();

            bf16x8 af[2], bfr[8];
#pragma unroll
            for (int rf = 0; rf < 2; ++rf)
                af[rf] = *(const bf16x8*)(Asb + SLADDR(wr * 32 + rf * 16 + l15, l4));
#pragma unroll
            for (int cf = 0; cf < 8; ++cf)
                bfr[cf] = *(const bf16x8*)(Bsb + SLADDR(wc * 128 + cf * 16 + l15, l4));
#pragma unroll
            for (int rf = 0; rf < 2; ++rf)
#pragma unroll
                for (int cf = 0; cf < 8; ++cf)
                    acc[rf][cf] = __builtin_amdgcn_mfma_f32_16x16x32_bf16(af[rf], bfr[cf], acc[rf][cf], 0, 0, 0);
        }
        lds_barrier();   // all reads of HIO-staging done before HIO result write

#pragma unroll
        for (int rf = 0; rf < 2; ++rf)
#pragma unroll
            for (int cf = 0; cf < 8; ++cf) {
                int j  = wc * 128 + cf * 16 + l15;
                int e0 = wr * 32 + rf * 16 + l4 * 4;
                s16x4 s;
#pragma unroll
                for (int r = 0; r < 4; ++r) s[r] = f2bf(acc[rf][cf][r] + bj[cf]);
                *(s16x4*)(pHIO + j * 256 + ((e0 * 2) ^ ((j & 7) << 4))) = s;
            }
        lds_barrier();
    }

    // ================= Phase 2: k3a -> inputs_lds =================
    {
        float bj[8];
#pragma unroll
        for (int cf = 0; cf < 8; ++cf) {
            int j = wc * 128 + cf * 16 + l15;
            bj[cf] = (j < 128) ? b_iah[j] : b_ioh[j - 128];
        }
        f32x4 acc[2][8];
#pragma unroll
        for (int rf = 0; rf < 2; ++rf)
#pragma unroll
            for (int cf = 0; cf < 8; ++cf) acc[rf][cf] = (f32x4){0.f,0.f,0.f,0.f};

        const float* Ab = A + (size_t)b * 128 * 256;
        float4 ra0, ra1, ra2, ra3;
        {
            const float* s0 = Ab + (size_t)srow * 256 +       sc4 * 8;
            const float* s1 = Ab + (size_t)srow * 256 + 128 + sc4 * 8;
            ra0 = ((const float4*)s0)[0]; ra1 = ((const float4*)s0)[1];
            ra2 = ((const float4*)s1)[0]; ra3 = ((const float4*)s1)[1];
        }

#pragma unroll 1
        for (int kt = 0; kt < 4; ++kt) {
            char* As0 = (kt & 1) ? pINP            : pSTG;
            char* As1 = (kt & 1) ? pINP + 8 * 1024 : pSTG + 8 * 1024;
            *(bf16x8*)(As0 + SLADDR(srow, sc4)) = pk8(ra0, ra1);
            *(bf16x8*)(As1 + SLADDR(srow, sc4)) = pk8(ra2, ra3);
            if (kt + 1 < 4) {
                const int k2 = kt + 1;
                const float* s0 = Ab + (size_t)srow * 256 +       k2 * 32 + sc4 * 8;
                const float* s1 = Ab + (size_t)srow * 256 + 128 + k2 * 32 + sc4 * 8;
                ra0 = ((const float4*)s0)[0]; ra1 = ((const float4*)s0)[1];
                ra2 = ((const float4*)s1)[0]; ra3 = ((const float4*)s1)[1];
            }
            lds_barrier();

            const char* Asel = wc ? As1 : As0;
            bf16x8 af[2], bfr[8];
#pragma unroll
            for (int rf = 0; rf < 2; ++rf)
                af[rf] = *(const bf16x8*)(Asel + SLADDR(wr * 32 + rf * 16 + l15, l4));
#pragma unroll
            for (int cf = 0; cf < 8; ++cf)
                bfr[cf] = t_frag(pHIO, wc * 128 + cf * 16 + l15, kt * 64 + l4 * 16);
#pragma unroll
            for (int rf = 0; rf < 2; ++rf)
#pragma unroll
                for (int cf = 0; cf < 8; ++cf)
                    acc[rf][cf] = __builtin_amdgcn_mfma_f32_16x16x32_bf16(af[rf], bfr[cf], acc[rf][cf], 0, 0, 0);
        }
        lds_barrier();   // all reads of INP-staging + HIO done before INP result write

#pragma unroll
        for (int rf = 0; rf < 2; ++rf)
#pragma unroll
            for (int cf = 0; cf < 8; ++cf) {
                int j = wc * 128 + cf * 16 + l15;
#pragma unroll
                for (int r = 0; r < 4; ++r) {
                    int n = wr * 32 + rf * 16 + l4 * 4 + r;
                    *(short*)(pINP + n * 512 + ((j * 2) ^ ((n & 7) << 4))) = f2bf(acc[rf][cf][r] + bj[cf]);
                }
            }
        lds_barrier();
    }

    // ================= Phase 3: k3b -> out =================
    {
        float br[4], bz[4], bi[4], bh_[4];
#pragma unroll
        for (int p = 0; p < 4; ++p) {
            int d = (wc * 4 + p) * 16 + l15;
            br[p] = bih[d]       + bhh[d];
            bz[p] = bih[128 + d] + bhh[128 + d];
            bi[p] = bih[256 + d];
            bh_[p]= bhh[256 + d];
        }
        f32x4 aR[2][4], aZ[2][4], aI[2][4], aH[2][4];
#pragma unroll
        for (int rf = 0; rf < 2; ++rf)
#pragma unroll
            for (int p = 0; p < 4; ++p) {
                aR[rf][p] = (f32x4){0.f,0.f,0.f,0.f};
                aZ[rf][p] = (f32x4){0.f,0.f,0.f,0.f};
                aI[rf][p] = (f32x4){0.f,0.f,0.f,0.f};
                aH[rf][p] = (f32x4){0.f,0.f,0.f,0.f};
            }

        float4 rb[6];
        float4 rh0, rh1;
        {
#pragma unroll
            for (int i = 0; i < 3; ++i) {
                int c = tid + 512 * i;
                int row = c >> 2, ch = c & 3;
                const float* wsrc = wih + (size_t)row * 256 + ch * 8;
                rb[2*i]   = ((const float4*)wsrc)[0];
                rb[2*i+1] = ((const float4*)wsrc)[1];
            }
        }

#pragma unroll 1
        for (int kt = 0; kt < 12; ++kt) {
            char* Bs3 = (kt & 1) ? pHIO : pSTG;
            char* HID = (kt & 1) ? pHIO + 40 * 1024 : pHIO + 32 * 1024;
            if (kt >= 8) {
                *(bf16x8*)(HID + SLADDR(srow, sc4)) = pk8(rh0, rh1);
            }
#pragma unroll
            for (int i = 0; i < 3; ++i) {
                int c = tid + 512 * i;
                int row = c >> 2, ch = c & 3;
                *(bf16x8*)(Bs3 + SLADDR(row, ch)) = pk8(rb[2*i], rb[2*i+1]);
            }
            if (kt + 1 < 12) {
                const int k2 = kt + 1;
#pragma unroll
                for (int i = 0; i < 3; ++i) {
                    int c = tid + 512 * i;
                    int row = c >> 2, ch = c & 3;
                    const float* wsrc = (k2 < 8)
                        ? (wih + (size_t)row * 256 + k2 * 32 + ch * 8)
                        : (whh + (size_t)row * 128 + (k2 - 8) * 32 + ch * 8);
                    rb[2*i]   = ((const float4*)wsrc)[0];
                    rb[2*i+1] = ((const float4*)wsrc)[1];
                }
                if (k2 >= 8) {
                    const float* src = hidden + (size_t)(m0 + srow) * 128 + (k2 - 8) * 32 + sc4 * 8;
                    rh0 = ((const float4*)src)[0]; rh1 = ((const float4*)src)[1];
                }
            }
            lds_barrier();

            bf16x8 a0, a1;
            if (kt < 8) {
                const int cb = kt * 64 + l4 * 16;
                a0 = t_frag512(pINP, wr * 32 +      l15, cb);
                a1 = t_frag512(pINP, wr * 32 + 16 + l15, cb);
            } else {
                a0 = *(const bf16x8*)(HID + SLADDR(wr * 32 +      l15, l4));
                a1 = *(const bf16x8*)(HID + SLADDR(wr * 32 + 16 + l15, l4));
            }
#pragma unroll
            for (int p = 0; p < 4; ++p) {
                int jb = (wc * 4 + p) * 16 + l15;
                bf16x8 bR = *(const bf16x8*)(Bs3 + SLADDR(      jb, l4));
                bf16x8 bZ = *(const bf16x8*)(Bs3 + SLADDR(128 + jb, l4));
                bf16x8 bN = *(const bf16x8*)(Bs3 + SLADDR(256 + jb, l4));
                aR[0][p] = __builtin_amdgcn_mfma_f32_16x16x32_bf16(a0, bR, aR[0][p], 0, 0, 0);
                aR[1][p] = __builtin_amdgcn_mfma_f32_16x16x32_bf16(a1, bR, aR[1][p], 0, 0, 0);
                aZ[0][p] = __builtin_amdgcn_mfma_f32_16x16x32_bf16(a0, bZ, aZ[0][p], 0, 0, 0);
                aZ[1][p] = __builtin_amdgcn_mfma_f32_16x16x32_bf16(a1, bZ, aZ[1][p], 0, 0, 0);
                if (kt < 8) {
                    aI[0][p] = __builtin_amdgcn_mfma_f32_16x16x32_bf16(a0, bN, aI[0][p], 0, 0, 0);
                    aI[1][p] = __builtin_amdgcn_mfma_f32_16x16x32_bf16(a1, bN, aI[1][p], 0, 0, 0);
                } else {
                    aH[0][p] = __builtin_amdgcn_mfma_f32_16x16x32_bf16(a0, bN, aH[0][p], 0, 0, 0);
                    aH[1][p] = __builtin_amdgcn_mfma_f32_16x16x32_bf16(a1, bN, aH[1][p], 0, 0, 0);
                }
            }
        }

#pragma unroll
        for (int rf = 0; rf < 2; ++rf)
#pragma unroll
            for (int p = 0; p < 4; ++p) {
                int d = (wc * 4 + p) * 16 + l15;
#pragma unroll
                for (int r = 0; r < 4; ++r) {
                    int m = m0 + wr * 32 + rf * 16 + l4 * 4 + r;
                    float hv = hidden[(size_t)m * 128 + d];
                    float rg = sigm(aR[rf][p][r] + br[p]);
                    float zg = sigm(aZ[rf][p][r] + bz[p]);
                    float ng = fast_tanh(aI[rf][p][r] + bi[p] + rg * (aH[rf][p][r] + bh_[p]));
                    out[(size_t)m * 128 + d] = (1.f - zg) * hv + zg * ng;
                }
            }
    }
}

// ---------------------------------------------------------------------------
extern "C" void kernel_launch(void* const* d_in, const int* in_sizes, int n_in,
                              void* d_out, int out_size, void* d_ws, size_t ws_size,
                              hipStream_t stream) {
    const float* A     = (const float*)d_in[0];
    const float* hidden= (const float*)d_in[1];
    const float* mi    = (const float*)d_in[2];
    const float* xa    = (const float*)d_in[3];
    const int*   len   = (const int*)  d_in[4];
    const float* gwih  = (const float*)d_in[5];
    const float* gwhh  = (const float*)d_in[6];
    const float* gbih  = (const float*)d_in[7];
    const float* gbhh  = (const float*)d_in[8];
    const float* wih   = (const float*)d_in[9];
    const float* whh   = (const float*)d_in[10];
    const float* bih   = (const float*)d_in[11];
    const float* bhh   = (const float*)d_in[12];
    const float* biah  = (const float*)d_in[13];
    const float* bioh  = (const float*)d_in[14];
    const float* w_in  = (const float*)d_in[15];
    const float* b_in  = (const float*)d_in[16];
    const float* w_out = (const float*)d_in[17];
    const float* b_out = (const float*)d_in[18];

    float* out = (float*)d_out;
    // ws layout (8.5 MB):
    //   [0, 8.39 MB):      mh bf16 [M][128]   (k1 -> k23)
    //   [8.39 MB, +128KB): perm int [M]       (k0 -> k1)
    short* mh   = (short*)d_ws;
    int*   perm = (int*)((char*)d_ws + (size_t)M_ * D_ * 2);

    k0_sort    <<<1,      1024, 0, stream>>>(len, perm);
    k1_gru_mfma<<<256,     512, 0, stream>>>(xa, len, perm, gwih, gwhh, gbih, gbhh, mh);
    k23_fused  <<<B_,      512, 0, stream>>>(A, hidden, mi, mh,
                                             w_in, b_in, w_out, b_out,
                                             biah, bioh, wih, whh, bih, bhh, out);
}

// Round 17
// 272.503 us; speedup vs baseline: 1.2945x; 1.0227x over previous
//
#include <hip/hip_runtime.h>
#include <math.h>

#define B_ 256
#define E_ 128
#define N_ 128
#define T_ 20
#define D_ 128
#define M_ (B_*E_)   // 32768 sequences

typedef __attribute__((ext_vector_type(8))) short bf16x8;
typedef __attribute__((ext_vector_type(4))) short s16x4;
typedef __attribute__((ext_vector_type(4))) float f32x4;
typedef __attribute__((ext_vector_type(4))) unsigned u32x4;

__device__ __forceinline__ float sigm(float x) { return 1.0f / (1.0f + __expf(-x)); }
__device__ __forceinline__ float fast_tanh(float x) {
    float e = __expf(2.f * x);
    return 1.f - 2.f / (e + 1.f);
}
__device__ __forceinline__ short f2bf(float f) {   // RNE float->bf16 (scalar)
    unsigned u = __builtin_bit_cast(unsigned, f);
    u += 0x7fffu + ((u >> 16) & 1u);
    return (short)(u >> 16);
}
// HW packed convert: 2 f32 -> 2 bf16 in one instruction (RNE).
__device__ __forceinline__ unsigned cvtpk(float lo, float hi) {
    unsigned r;
    asm("v_cvt_pk_bf16_f32 %0, %1, %2" : "=v"(r) : "v"(lo), "v"(hi));
    return r;
}
__device__ __forceinline__ bf16x8 pk8(float4 a, float4 b) {
    u32x4 u = { cvtpk(a.x,a.y), cvtpk(a.z,a.w), cvtpk(b.x,b.y), cvtpk(b.z,b.w) };
    return __builtin_bit_cast(bf16x8, u);
}
__device__ __forceinline__ bf16x8 cvt8(const float* __restrict__ p) {
    float4 u = *(const float4*)p;
    float4 v = *(const float4*)(p + 4);
    return pk8(u, v);
}

// [rows][32k] bf16 slice, 64 B/row; chunk-XOR swizzle.
#define SLADDR(row, chunk) ((row) * 64 + ((((chunk) ^ ((row) >> 1)) & 3) << 4))

// [rows][128 cols bf16] tile, 256 B/row, byte-XOR swizzle.
__device__ __forceinline__ bf16x8 t_frag(const char* base, int row, int cb) {
    return *(const bf16x8*)(base + row * 256 + (cb ^ ((row & 7) << 4)));
}
// [rows][256 cols bf16] tile, 512 B/row, byte-XOR swizzle.
__device__ __forceinline__ bf16x8 t_frag512(const char* base, int row, int cb) {
    return *(const bf16x8*)(base + row * 512 + (cb ^ ((row & 7) << 4)));
}

// LDS-only barrier: drain LDS ops, sync, but DON'T drain vmcnt.
__device__ __forceinline__ void lds_barrier() {
    asm volatile("s_waitcnt lgkmcnt(0)" ::: "memory");
    __builtin_amdgcn_s_barrier();
    asm volatile("" ::: "memory");
}

// ---------------------------------------------------------------------------
// K0: deterministic counting sort of sequence indices by len (bins 1..20).
// v2: scatter keeps bin cursors in REGISTERS (lane b-1 owns bin b's cursor;
// __shfl broadcast + lane-local popcount update) — no LDS round-trips in
// the loop. Output permutation identical to v1 (bin-major, wave-minor,
// lane-order within wave). Within each 64-chunk lens are NON-DECREASING.
// ---------------------------------------------------------------------------
__global__ __launch_bounds__(1024) void k0_sort(
    const int* __restrict__ len, int* __restrict__ perm)
{
    __shared__ int wavehist[16][21];
    __shared__ int wavebase[16][21];
    const int tid  = threadIdx.x;
    const int lane = tid & 63;
    const int w    = tid >> 6;

    // ---- histogram (register counters via ballot) ----
    int cnt = 0;
#pragma unroll 1
    for (int it = 0; it < 32; ++it) {
        int v = len[w * 2048 + it * 64 + lane];
#pragma unroll
        for (int b = 1; b <= 20; ++b) {
            unsigned long long mask = __ballot(v == b);
            if (lane == b - 1) cnt += __popcll(mask);
        }
    }
    if (lane < 20) wavehist[w][lane + 1] = cnt;
    __syncthreads();

    // ---- prefix (bin-major, wave-minor) ----
    if (tid == 0) {
        int run = 0;
        for (int b = 1; b <= 20; ++b)
            for (int wv = 0; wv < 16; ++wv) {
                int c = wavehist[wv][b];
                wavebase[wv][b] = run;
                run += c;
            }
    }
    __syncthreads();

    // ---- scatter with register cursors ----
    int cur = (lane < 20) ? wavebase[w][lane + 1] : 0;
#pragma unroll 1
    for (int it = 0; it < 32; ++it) {
        int idx = w * 2048 + it * 64 + lane;
        int v = len[idx];
#pragma unroll 1
        for (int b = 1; b <= 20; ++b) {
            unsigned long long mask = __ballot(v == b);
            if (mask) {
                int base = __shfl(cur, b - 1, 64);
                if (v == b) {
                    int rank = __popcll(mask & ((1ull << lane) - 1ull));
                    perm[base + rank] = idx;
                }
                if (lane == b - 1) cur += __popcll(mask);
            }
        }
    }
}

// ---------------------------------------------------------------------------
// K1: persistent MFMA micro-GRU, software-pipelined X phase.
// (byte-identical to round 13/14/16 — proven)
// ---------------------------------------------------------------------------
__global__ __launch_bounds__(512, 2) void k1_gru_mfma(
    const float* __restrict__ xa, const int* __restrict__ len,
    const int* __restrict__ perm,
    const float* __restrict__ wih, const float* __restrict__ whh,
    const float* __restrict__ bih, const float* __restrict__ bhh,
    short* __restrict__ mh)        // bf16 [M][128]
{
    __shared__ __align__(16) char XbB[3][64 * 256];
    __shared__ __align__(16) char Hb0[64 * 256];
    __shared__ __align__(16) char Hb1[64 * 256];
    __shared__ int pidx[64];
    __shared__ int lens_s[64];

    const int tid = threadIdx.x;
    const int l   = tid & 63;
    const int w   = tid >> 6;     // wave id 0..7 = d-tile
    const int l15 = l & 15;
    const int l4  = l >> 4;

    bf16x8 wf[2][3][4];
#pragma unroll
    for (int s = 0; s < 2; ++s) {
        const float* W = s ? whh : wih;
#pragma unroll
        for (int g = 0; g < 3; ++g) {
            int grow = g * 128 + w * 16 + l15;
#pragma unroll
            for (int kt = 0; kt < 4; ++kt)
                wf[s][g][kt] = cvt8(W + (size_t)grow * 128 + kt * 32 + l4 * 8);
        }
    }

    const int dcol = w * 16 + l15;
    const float brz = bih[dcol]       + bhh[dcol];
    const float bzz = bih[128 + dcol] + bhh[128 + dcol];
    const float bin_= bih[256 + dcol];
    const float bhn_= bhh[256 + dcol];
    const f32x4 bR4 = {brz, brz, brz, brz};
    const f32x4 bZ4 = {bzz, bzz, bzz, bzz};
    const f32x4 bI4 = {bin_, bin_, bin_, bin_};
    const f32x4 bH4 = {bhn_, bhn_, bhn_, bhn_};

    const int sr0 = tid >> 4;          // 0..31
    const int sc8 = (tid & 15) * 8;    // col in elems
    const int lbA = sr0 * 256 + ((sc8 * 2) ^ ((sr0 & 7) << 4));
    const int lbB = (sr0 + 32) * 256 + ((sc8 * 2) ^ (((sr0 + 32) & 7) << 4));

#pragma unroll 1
    for (int pass = 0; pass < 2; ++pass) {
        const int chunk = pass ? (511 - (int)blockIdx.x) : (int)blockIdx.x;

        __syncthreads();   // previous pass fully done with pidx/tiles
        if (tid < 64) {
            int p = perm[chunk * 64 + tid];
            pidx[tid]   = p;
            lens_s[tid] = len[p];
        }
        __syncthreads();

        int lenv[16];
#pragma unroll
        for (int mt = 0; mt < 4; ++mt)
#pragma unroll
            for (int r = 0; r < 4; ++r)
                lenv[mt * 4 + r] = lens_s[mt * 16 + l4 * 4 + r];

        const int Lmax = lens_s[63];   // sorted chunk: last element is max

        const int rA = pidx[sr0];
        const int rB = pidx[sr0 + 32];
        const float* xbA = xa + (size_t)rA * (T_ * D_) + sc8;
        const float* xbB = xa + (size_t)rB * (T_ * D_) + sc8;

        // prologue: stage X0 -> buf0, X1 -> buf1; prefetch X2
        {
            const float4* pA = (const float4*)xbA;
            const float4* pB = (const float4*)xbB;
            *(bf16x8*)(XbB[0] + lbA) = pk8(pA[0], pA[1]);
            *(bf16x8*)(XbB[0] + lbB) = pk8(pB[0], pB[1]);
            const float4* qA = (const float4*)(xbA + D_);
            const float4* qB = (const float4*)(xbB + D_);
            *(bf16x8*)(XbB[1] + lbA) = pk8(qA[0], qA[1]);
            *(bf16x8*)(XbB[1] + lbB) = pk8(qB[0], qB[1]);
        }
        float4 xa0, xa1, xb0v, xb1v;
        {
            const float4* qA = (const float4*)(xbA + 2 * D_);
            const float4* qB = (const float4*)(xbB + 2 * D_);
            xa0 = qA[0]; xa1 = qA[1]; xb0v = qB[0]; xb1v = qB[1];
        }
        lds_barrier();   // X0, X1 visible

        // seed acc with X-phase(0) (bias in C at kt=0); aH = bias (h=0)
        f32x4 aR[4], aZ[4], aI[4], aH[4];
        {
            const char* X0 = XbB[0];
            const int cb0 = l4 * 16;
#pragma unroll
            for (int mt = 0; mt < 4; ++mt) {
                bf16x8 a = t_frag(X0, mt * 16 + l15, cb0);
                aR[mt] = __builtin_amdgcn_mfma_f32_16x16x32_bf16(a, wf[0][0][0], bR4, 0, 0, 0);
                aZ[mt] = __builtin_amdgcn_mfma_f32_16x16x32_bf16(a, wf[0][1][0], bZ4, 0, 0, 0);
                aI[mt] = __builtin_amdgcn_mfma_f32_16x16x32_bf16(a, wf[0][2][0], bI4, 0, 0, 0);
            }
#pragma unroll
            for (int kt = 1; kt < 4; ++kt) {
                const int cb = kt * 64 + l4 * 16;
#pragma unroll
                for (int mt = 0; mt < 4; ++mt) {
                    bf16x8 a = t_frag(X0, mt * 16 + l15, cb);
                    aR[mt] = __builtin_amdgcn_mfma_f32_16x16x32_bf16(a, wf[0][0][kt], aR[mt], 0, 0, 0);
                    aZ[mt] = __builtin_amdgcn_mfma_f32_16x16x32_bf16(a, wf[0][1][kt], aZ[mt], 0, 0, 0);
                    aI[mt] = __builtin_amdgcn_mfma_f32_16x16x32_bf16(a, wf[0][2][kt], aI[mt], 0, 0, 0);
                }
            }
#pragma unroll
            for (int mt = 0; mt < 4; ++mt) aH[mt] = bH4;
        }

        float hm[4][4];
#pragma unroll
        for (int mt = 0; mt < 4; ++mt)
#pragma unroll
            for (int r = 0; r < 4; ++r) hm[mt][r] = 0.f;

        char* Xr_ = XbB[1];
        char* Xw_ = XbB[2];
        char* Xs_ = XbB[0];
        char* Hc = Hb0; char* Hn = Hb1;

#pragma unroll 1
        for (int t = 0; t < Lmax; ++t) {
            // a) stage X(t+2); issue prefetch X(t+3)
            if (t + 2 < Lmax) {
                *(bf16x8*)(Xw_ + lbA) = pk8(xa0, xa1);
                *(bf16x8*)(Xw_ + lbB) = pk8(xb0v, xb1v);
            }
            if (t + 3 < Lmax) {
                const float4* qA = (const float4*)(xbA + (t + 3) * D_);
                const float4* qB = (const float4*)(xbB + (t + 3) * D_);
                xa0 = qA[0]; xa1 = qA[1]; xb0v = qB[0]; xb1v = qB[1];
            }

            // b) H-phase MFMA(t)
            if (t > 0) {
                const int cb0 = l4 * 16;
#pragma unroll
                for (int mt = 0; mt < 4; ++mt) {
                    bf16x8 a = t_frag(Hc, mt * 16 + l15, cb0);
                    aR[mt] = __builtin_amdgcn_mfma_f32_16x16x32_bf16(a, wf[1][0][0], aR[mt], 0, 0, 0);
                    aZ[mt] = __builtin_amdgcn_mfma_f32_16x16x32_bf16(a, wf[1][1][0], aZ[mt], 0, 0, 0);
                    aH[mt] = __builtin_amdgcn_mfma_f32_16x16x32_bf16(a, wf[1][2][0], bH4, 0, 0, 0);
                }
#pragma unroll
                for (int kt = 1; kt < 4; ++kt) {
                    const int cb = kt * 64 + l4 * 16;
#pragma unroll
                    for (int mt = 0; mt < 4; ++mt) {
                        bf16x8 a = t_frag(Hc, mt * 16 + l15, cb);
                        aR[mt] = __builtin_amdgcn_mfma_f32_16x16x32_bf16(a, wf[1][0][kt], aR[mt], 0, 0, 0);
                        aZ[mt] = __builtin_amdgcn_mfma_f32_16x16x32_bf16(a, wf[1][1][kt], aZ[mt], 0, 0, 0);
                        aH[mt] = __builtin_amdgcn_mfma_f32_16x16x32_bf16(a, wf[1][2][kt], aH[mt], 0, 0, 0);
                    }
                }
            }

            // c) per-mt: epilogue(t) -> h-write(t+1) -> re-seed X-phase(t+1)
            const bool more = (t + 1 < Lmax);
#pragma unroll
            for (int mt = 0; mt < 4; ++mt) {
#pragma unroll
                for (int r = 0; r < 4; ++r) {
                    float rr = sigm(aR[mt][r]);
                    float zz = sigm(aZ[mt][r]);
                    float nn = fast_tanh(aI[mt][r] + rr * aH[mt][r]);
                    float hold = hm[mt][r];
                    float hnew = nn + zz * (hold - nn);
                    hm[mt][r] = (t < lenv[mt * 4 + r]) ? hnew : hold;
                }
                if (more) {
#pragma unroll
                    for (int rp = 0; rp < 4; rp += 2) {
                        unsigned pk = cvtpk(hm[mt][rp], hm[mt][rp + 1]);
                        int row0 = mt * 16 + l4 * 4 + rp;
                        int row1 = row0 + 1;
                        *(short*)(Hn + row0 * 256 + ((dcol * 2) ^ ((row0 & 7) << 4))) = (short)(pk & 0xffff);
                        *(short*)(Hn + row1 * 256 + ((dcol * 2) ^ ((row1 & 7) << 4))) = (short)(pk >> 16);
                    }
                    {
                        const int cb0 = l4 * 16;
                        bf16x8 a = t_frag(Xr_, mt * 16 + l15, cb0);
                        aR[mt] = __builtin_amdgcn_mfma_f32_16x16x32_bf16(a, wf[0][0][0], bR4, 0, 0, 0);
                        aZ[mt] = __builtin_amdgcn_mfma_f32_16x16x32_bf16(a, wf[0][1][0], bZ4, 0, 0, 0);
                        aI[mt] = __builtin_amdgcn_mfma_f32_16x16x32_bf16(a, wf[0][2][0], bI4, 0, 0, 0);
                    }
#pragma unroll
                    for (int kt = 1; kt < 4; ++kt) {
                        const int cb = kt * 64 + l4 * 16;
                        bf16x8 a = t_frag(Xr_, mt * 16 + l15, cb);
                        aR[mt] = __builtin_amdgcn_mfma_f32_16x16x32_bf16(a, wf[0][0][kt], aR[mt], 0, 0, 0);
                        aZ[mt] = __builtin_amdgcn_mfma_f32_16x16x32_bf16(a, wf[0][1][kt], aZ[mt], 0, 0, 0);
                        aI[mt] = __builtin_amdgcn_mfma_f32_16x16x32_bf16(a, wf[0][2][kt], aI[mt], 0, 0, 0);
                    }
                }
            }

            // d) barrier; rotate X buffers; swap H buffers
            if (more) {
                lds_barrier();
                char* tmp = Xr_; Xr_ = Xw_; Xw_ = Xs_; Xs_ = tmp;
                char* th = Hc; Hc = Hn; Hn = th;
            }
        }

        // final h -> mh (bf16, scattered by perm)
#pragma unroll
        for (int mt = 0; mt < 4; ++mt) {
#pragma unroll
            for (int r = 0; r < 4; ++r) {
                int m = pidx[mt * 16 + l4 * 4 + r];
                mh[(size_t)m * 128 + dcol] = f2bf(hm[mt][r]);
            }
        }
    }
}

// ---------------------------------------------------------------------------
// K23 (fused k2 + k3a + k3b), pipelined + double-buffered staging.
// (byte-identical to round 16 — proven)
// ---------------------------------------------------------------------------
__global__ __launch_bounds__(512) void k23_fused(
    const float* __restrict__ A, const float* __restrict__ hidden,
    const float* __restrict__ mi, const short* __restrict__ mh,
    const float* __restrict__ w_in, const float* __restrict__ b_in,
    const float* __restrict__ w_out, const float* __restrict__ b_out,
    const float* __restrict__ b_iah, const float* __restrict__ b_ioh,
    const float* __restrict__ wih, const float* __restrict__ whh,
    const float* __restrict__ bih, const float* __restrict__ bhh,
    float* __restrict__ out)
{
    __shared__ __align__(16) char HIO[64 * 1024];
    __shared__ __align__(16) char INP[64 * 1024];
    __shared__ __align__(16) char STG[24 * 1024];

    const int tid = threadIdx.x;
    const int l = tid & 63, w = tid >> 6;
    const int l15 = l & 15, l4 = l >> 4;
    const int wr = w >> 1, wc = w & 1;
    const int b  = blockIdx.x;
    const int m0 = b * 128;

    char* const pSTG = STG;   // generic-AS copies (avoid static-init addrspacecast)
    char* const pHIO = HIO;
    char* const pINP = INP;

    const int srow = tid >> 2, sc4 = tid & 3;
    const int brow = tid >> 1, bh  = tid & 1;

    // ================= Phase 1: k2 -> hioT_lds =================
    {
        float bj[8];
#pragma unroll
        for (int cf = 0; cf < 8; ++cf) {
            int j = wc * 128 + cf * 16 + l15;
            bj[cf] = (j < 128) ? b_in[j] : b_out[j - 128];
        }
        f32x4 acc[2][8];
#pragma unroll
        for (int rf = 0; rf < 2; ++rf)
#pragma unroll
            for (int cf = 0; cf < 8; ++cf) acc[rf][cf] = (f32x4){0.f,0.f,0.f,0.f};

        float4 ra0, ra1; bf16x8 rah;
        float4 rb0, rb1, rb2, rb3;
        {
            const float* asrc = mi + (size_t)(m0 + srow) * 128 + sc4 * 8;
            ra0 = ((const float4*)asrc)[0]; ra1 = ((const float4*)asrc)[1];
            const float* wsrc = (brow < 128)
                ? (w_in  + (size_t)brow * 256 + bh * 16)
                : (w_out + (size_t)(brow - 128) * 256 + bh * 16);
            rb0 = ((const float4*)wsrc)[0]; rb1 = ((const float4*)wsrc)[1];
            rb2 = ((const float4*)wsrc)[2]; rb3 = ((const float4*)wsrc)[3];
        }

#pragma unroll 1
        for (int kt = 0; kt < 8; ++kt) {
            char* Asb = (kt & 1) ? pHIO            : pSTG;
            char* Bsb = (kt & 1) ? pHIO + 8 * 1024 : pSTG + 8 * 1024;
            *(bf16x8*)(Asb + SLADDR(srow, sc4)) = (kt < 4) ? pk8(ra0, ra1) : rah;
            *(bf16x8*)(Bsb + SLADDR(brow, bh * 2    )) = pk8(rb0, rb1);
            *(bf16x8*)(Bsb + SLADDR(brow, bh * 2 + 1)) = pk8(rb2, rb3);

            if (kt + 1 < 8) {
                const int k2 = kt + 1;
                if (k2 < 4) {
                    const float* asrc = mi + (size_t)(m0 + srow) * 128 + k2 * 32 + sc4 * 8;
                    ra0 = ((const float4*)asrc)[0]; ra1 = ((const float4*)asrc)[1];
                } else {
                    rah = *(const bf16x8*)(mh + (size_t)(m0 + srow) * 128 + (k2 - 4) * 32 + sc4 * 8);
                }
                const float* wsrc = (brow < 128)
                    ? (w_in  + (size_t)brow * 256 + k2 * 32 + bh * 16)
                    : (w_out + (size_t)(brow - 128) * 256 + k2 * 32 + bh * 16);
                rb0 = ((const float4*)wsrc)[0]; rb1 = ((const float4*)wsrc)[1];
                rb2 = ((const float4*)wsrc)[2]; rb3 = ((const float4*)wsrc)[3];
            }
            lds_barrier();

            bf16x8 af[2], bfr[8];
#pragma unroll
            for (int rf = 0; rf < 2; ++rf)
                af[rf] = *(const bf16x8*)(Asb + SLADDR(wr * 32 + rf * 16 + l15, l4));
#pragma unroll
            for (int cf = 0; cf < 8; ++cf)
                bfr[cf] = *(const bf16x8*)(Bsb + SLADDR(wc * 128 + cf * 16 + l15, l4));
#pragma unroll
            for (int rf = 0; rf < 2; ++rf)
#pragma unroll
                for (int cf = 0; cf < 8; ++cf)
                    acc[rf][cf] = __builtin_amdgcn_mfma_f32_16x16x32_bf16(af[rf], bfr[cf], acc[rf][cf], 0, 0, 0);
        }
        lds_barrier();   // all reads of HIO-staging done before HIO result write

#pragma unroll
        for (int rf = 0; rf < 2; ++rf)
#pragma unroll
            for (int cf = 0; cf < 8; ++cf) {
                int j  = wc * 128 + cf * 16 + l15;
                int e0 = wr * 32 + rf * 16 + l4 * 4;
                s16x4 s;
#pragma unroll
                for (int r = 0; r < 4; ++r) s[r] = f2bf(acc[rf][cf][r] + bj[cf]);
                *(s16x4*)(pHIO + j * 256 + ((e0 * 2) ^ ((j & 7) << 4))) = s;
            }
        lds_barrier();
    }

    // ================= Phase 2: k3a -> inputs_lds =================
    {
        float bj[8];
#pragma unroll
        for (int cf = 0; cf < 8; ++cf) {
            int j = wc * 128 + cf * 16 + l15;
            bj[cf] = (j < 128) ? b_iah[j] : b_ioh[j - 128];
        }
        f32x4 acc[2][8];
#pragma unroll
        for (int rf = 0; rf < 2; ++rf)
#pragma unroll
            for (int cf = 0; cf < 8; ++cf) acc[rf][cf] = (f32x4){0.f,0.f,0.f,0.f};

        const float* Ab = A + (size_t)b * 128 * 256;
        float4 ra0, ra1, ra2, ra3;
        {
            const float* s0 = Ab + (size_t)srow * 256 +       sc4 * 8;
            const float* s1 = Ab + (size_t)srow * 256 + 128 + sc4 * 8;
            ra0 = ((const float4*)s0)[0]; ra1 = ((const float4*)s0)[1];
            ra2 = ((const float4*)s1)[0]; ra3 = ((const float4*)s1)[1];
        }

#pragma unroll 1
        for (int kt = 0; kt < 4; ++kt) {
            char* As0 = (kt & 1) ? pINP            : pSTG;
            char* As1 = (kt & 1) ? pINP + 8 * 1024 : pSTG + 8 * 1024;
            *(bf16x8*)(As0 + SLADDR(srow, sc4)) = pk8(ra0, ra1);
            *(bf16x8*)(As1 + SLADDR(srow, sc4)) = pk8(ra2, ra3);
            if (kt + 1 < 4) {
                const int k2 = kt + 1;
                const float* s0 = Ab + (size_t)srow * 256 +       k2 * 32 + sc4 * 8;
                const float* s1 = Ab + (size_t)srow * 256 + 128 + k2 * 32 + sc4 * 8;
                ra0 = ((const float4*)s0)[0]; ra1 = ((const float4*)s0)[1];
                ra2 = ((const float4*)s1)[0]; ra3 = ((const float4*)s1)[1];
            }
            lds_barrier();

            const char* Asel = wc ? As1 : As0;
            bf16x8 af[2], bfr[8];
#pragma unroll
            for (int rf = 0; rf < 2; ++rf)
                af[rf] = *(const bf16x8*)(Asel + SLADDR(wr * 32 + rf * 16 + l15, l4));
#pragma unroll
            for (int cf = 0; cf < 8; ++cf)
                bfr[cf] = t_frag(pHIO, wc * 128 + cf * 16 + l15, kt * 64 + l4 * 16);
#pragma unroll
            for (int rf = 0; rf < 2; ++rf)
#pragma unroll
                for (int cf = 0; cf < 8; ++cf)
                    acc[rf][cf] = __builtin_amdgcn_mfma_f32_16x16x32_bf16(af[rf], bfr[cf], acc[rf][cf], 0, 0, 0);
        }
        lds_barrier();   // all reads of INP-staging + HIO done before INP result write

#pragma unroll
        for (int rf = 0; rf < 2; ++rf)
#pragma unroll
            for (int cf = 0; cf < 8; ++cf) {
                int j = wc * 128 + cf * 16 + l15;
#pragma unroll
                for (int r = 0; r < 4; ++r) {
                    int n = wr * 32 + rf * 16 + l4 * 4 + r;
                    *(short*)(pINP + n * 512 + ((j * 2) ^ ((n & 7) << 4))) = f2bf(acc[rf][cf][r] + bj[cf]);
                }
            }
        lds_barrier();
    }

    // ================= Phase 3: k3b -> out =================
    {
        float br[4], bz[4], bi[4], bh_[4];
#pragma unroll
        for (int p = 0; p < 4; ++p) {
            int d = (wc * 4 + p) * 16 + l15;
            br[p] = bih[d]       + bhh[d];
            bz[p] = bih[128 + d] + bhh[128 + d];
            bi[p] = bih[256 + d];
            bh_[p]= bhh[256 + d];
        }
        f32x4 aR[2][4], aZ[2][4], aI[2][4], aH[2][4];
#pragma unroll
        for (int rf = 0; rf < 2; ++rf)
#pragma unroll
            for (int p = 0; p < 4; ++p) {
                aR[rf][p] = (f32x4){0.f,0.f,0.f,0.f};
                aZ[rf][p] = (f32x4){0.f,0.f,0.f,0.f};
                aI[rf][p] = (f32x4){0.f,0.f,0.f,0.f};
                aH[rf][p] = (f32x4){0.f,0.f,0.f,0.f};
            }

        float4 rb[6];
        float4 rh0, rh1;
        {
#pragma unroll
            for (int i = 0; i < 3; ++i) {
                int c = tid + 512 * i;
                int row = c >> 2, ch = c & 3;
                const float* wsrc = wih + (size_t)row * 256 + ch * 8;
                rb[2*i]   = ((const float4*)wsrc)[0];
                rb[2*i+1] = ((const float4*)wsrc)[1];
            }
        }

#pragma unroll 1
        for (int kt = 0; kt < 12; ++kt) {
            char* Bs3 = (kt & 1) ? pHIO : pSTG;
            char* HID = (kt & 1) ? pHIO + 40 * 1024 : pHIO + 32 * 1024;
            if (kt >= 8) {
                *(bf16x8*)(HID + SLADDR(srow, sc4)) = pk8(rh0, rh1);
            }
#pragma unroll
            for (int i = 0; i < 3; ++i) {
                int c = tid + 512 * i;
                int row = c >> 2, ch = c & 3;
                *(bf16x8*)(Bs3 + SLADDR(row, ch)) = pk8(rb[2*i], rb[2*i+1]);
            }
            if (kt + 1 < 12) {
                const int k2 = kt + 1;
#pragma unroll
                for (int i = 0; i < 3; ++i) {
                    int c = tid + 512 * i;
                    int row = c >> 2, ch = c & 3;
                    const float* wsrc = (k2 < 8)
                        ? (wih + (size_t)row * 256 + k2 * 32 + ch * 8)
                        : (whh + (size_t)row * 128 + (k2 - 8) * 32 + ch * 8);
                    rb[2*i]   = ((const float4*)wsrc)[0];
                    rb[2*i+1] = ((const float4*)wsrc)[1];
                }
                if (k2 >= 8) {
                    const float* src = hidden + (size_t)(m0 + srow) * 128 + (k2 - 8) * 32 + sc4 * 8;
                    rh0 = ((const float4*)src)[0]; rh1 = ((const float4*)src)[1];
                }
            }
            lds_barrier();

            bf16x8 a0, a1;
            if (kt < 8) {
                const int cb = kt * 64 + l4 * 16;
                a0 = t_frag512(pINP, wr * 32 +      l15, cb);
                a1 = t_frag512(pINP, wr * 32 + 16 + l15, cb);
            } else {
                a0 = *(const bf16x8*)(HID + SLADDR(wr * 32 +      l15, l4));
                a1 = *(const bf16x8*)(HID + SLADDR(wr * 32 + 16 + l15, l4));
            }
#pragma unroll
            for (int p = 0; p < 4; ++p) {
                int jb = (wc * 4 + p) * 16 + l15;
                bf16x8 bR = *(const bf16x8*)(Bs3 + SLADDR(      jb, l4));
                bf16x8 bZ = *(const bf16x8*)(Bs3 + SLADDR(128 + jb, l4));
                bf16x8 bN = *(const bf16x8*)(Bs3 + SLADDR(256 + jb, l4));
                aR[0][p] = __builtin_amdgcn_mfma_f32_16x16x32_bf16(a0, bR, aR[0][p], 0, 0, 0);
                aR[1][p] = __builtin_amdgcn_mfma_f32_16x16x32_bf16(a1, bR, aR[1][p], 0, 0, 0);
                aZ[0][p] = __builtin_amdgcn_mfma_f32_16x16x32_bf16(a0, bZ, aZ[0][p], 0, 0, 0);
                aZ[1][p] = __builtin_amdgcn_mfma_f32_16x16x32_bf16(a1, bZ, aZ[1][p], 0, 0, 0);
                if (kt < 8) {
                    aI[0][p] = __builtin_amdgcn_mfma_f32_16x16x32_bf16(a0, bN, aI[0][p], 0, 0, 0);
                    aI[1][p] = __builtin_amdgcn_mfma_f32_16x16x32_bf16(a1, bN, aI[1][p], 0, 0, 0);
                } else {
                    aH[0][p] = __builtin_amdgcn_mfma_f32_16x16x32_bf16(a0, bN, aH[0][p], 0, 0, 0);
                    aH[1][p] = __builtin_amdgcn_mfma_f32_16x16x32_bf16(a1, bN, aH[1][p], 0, 0, 0);
                }
            }
        }

#pragma unroll
        for (int rf = 0; rf < 2; ++rf)
#pragma unroll
            for (int p = 0; p < 4; ++p) {
                int d = (wc * 4 + p) * 16 + l15;
#pragma unroll
                for (int r = 0; r < 4; ++r) {
                    int m = m0 + wr * 32 + rf * 16 + l4 * 4 + r;
                    float hv = hidden[(size_t)m * 128 + d];
                    float rg = sigm(aR[rf][p][r] + br[p]);
                    float zg = sigm(aZ[rf][p][r] + bz[p]);
                    float ng = fast_tanh(aI[rf][p][r] + bi[p] + rg * (aH[rf][p][r] + bh_[p]));
                    out[(size_t)m * 128 + d] = (1.f - zg) * hv + zg * ng;
                }
            }
    }
}

// ---------------------------------------------------------------------------
extern "C" void kernel_launch(void* const* d_in, const int* in_sizes, int n_in,
                              void* d_out, int out_size, void* d_ws, size_t ws_size,
                              hipStream_t stream) {
    const float* A     = (const float*)d_in[0];
    const float* hidden= (const float*)d_in[1];
    const float* mi    = (const float*)d_in[2];
    const float* xa    = (const float*)d_in[3];
    const int*   len   = (const int*)  d_in[4];
    const float* gwih  = (const float*)d_in[5];
    const float* gwhh  = (const float*)d_in[6];
    const float* gbih  = (const float*)d_in[7];
    const float* gbhh  = (const float*)d_in[8];
    const float* wih   = (const float*)d_in[9];
    const float* whh   = (const float*)d_in[10];
    const float* bih   = (const float*)d_in[11];
    const float* bhh   = (const float*)d_in[12];
    const float* biah  = (const float*)d_in[13];
    const float* bioh  = (const float*)d_in[14];
    const float* w_in  = (const float*)d_in[15];
    const float* b_in  = (const float*)d_in[16];
    const float* w_out = (const float*)d_in[17];
    const float* b_out = (const float*)d_in[18];

    float* out = (float*)d_out;
    // ws layout (8.5 MB):
    //   [0, 8.39 MB):      mh bf16 [M][128]   (k1 -> k23)
    //   [8.39 MB, +128KB): perm int [M]       (k0 -> k1)
    short* mh   = (short*)d_ws;
    int*   perm = (int*)((char*)d_ws + (size_t)M_ * D_ * 2);

    k0_sort    <<<1,      1024, 0, stream>>>(len, perm);
    k1_gru_mfma<<<256,     512, 0, stream>>>(xa, len, perm, gwih, gwhh, gbih, gbhh, mh);
    k23_fused  <<<B_,      512, 0, stream>>>(A, hidden, mi, mh,
                                             w_in, b_in, w_out, b_out,
                                             biah, bioh, wih, whh, bih, bhh, out);
}